// Round 8
// baseline (863.399 us; speedup 1.0000x reference)
//
#include <hip/hip_runtime.h>
#include <hip/hip_bf16.h>

#define N_NODES 30000
#define N_EDGES 510000
#define K_DIM   128

typedef short bf16x8 __attribute__((ext_vector_type(8)));
typedef float f32x4  __attribute__((ext_vector_type(4)));
typedef unsigned short u16x8 __attribute__((ext_vector_type(8)));

__device__ __forceinline__ unsigned short f2bf(float f) {
  __hip_bfloat16 h = __float2bfloat16(f);
  return *(unsigned short*)&h;
}
__device__ __forceinline__ float bf2f(unsigned short u) {
  return __uint_as_float(((unsigned)u) << 16);
}

// ---------------- both W transposes (K x M fp32) -> (M x K bf16) ----------------
__global__ void transpose_w_kernel(const float* __restrict__ W1, unsigned short* __restrict__ Wt1,
                                   const float* __restrict__ W2, unsigned short* __restrict__ Wt2) {
  int i = blockIdx.x * blockDim.x + threadIdx.x;
  if (i < 128 * 256) {
    int k = i >> 8, m = i & 255;
    Wt1[m * 128 + k] = f2bf(W1[i]);
  } else if (i < 128 * 256 + 128 * 128) {
    int j = i - 128 * 256;
    int k = j >> 7, m = j & 127;
    Wt2[m * 128 + k] = f2bf(W2[j]);
  }
}

// ---------------- degree for both snapshots ----------------
__global__ void deg_kernel(const int* __restrict__ ei, int* __restrict__ deg0,
                           int* __restrict__ deg1, int e) {
  int i = blockIdx.x * blockDim.x + threadIdx.x;
  if (i < 2 * e) {
    int t = i >= e ? 1 : 0;
    int j = i - t * e;
    int d = ei[(size_t)t * 2 * e + e + j];
    atomicAdd(&(t ? deg1 : deg0)[d], 1);
  }
}

// ---------------- exclusive scan (3-phase), one block per snapshot ----------------
__global__ __launch_bounds__(1024) void scan_kernel(const int* __restrict__ deg0, int* __restrict__ off0, int* __restrict__ cur0,
                                                    const int* __restrict__ deg1, int* __restrict__ off1, int* __restrict__ cur1,
                                                    int n) {
  const int* deg = blockIdx.x ? deg1 : deg0;
  int* off = blockIdx.x ? off1 : off0;
  int* cur = blockIdx.x ? cur1 : cur0;
  const int CHUNK = 30;  // 1024*30 >= 30000
  __shared__ int wsum[16];
  int tid = threadIdx.x;
  int base = tid * CHUNK;
  int sum = 0;
  for (int i = 0; i < CHUNK; i++)
    if (base + i < n) sum += deg[base + i];
  int lane = tid & 63, wid = tid >> 6;
  int incl = sum;
#pragma unroll
  for (int o = 1; o < 64; o <<= 1) {
    int v = __shfl_up(incl, o);
    if (lane >= o) incl += v;
  }
  if (lane == 63) wsum[wid] = incl;
  __syncthreads();
  if (tid == 0) {
    int run = 0;
    for (int w = 0; w < 16; w++) { int v = wsum[w]; wsum[w] = run; run += v; }
  }
  __syncthreads();
  int run = incl - sum + wsum[wid];
  for (int i = 0; i < CHUNK; i++) {
    if (base + i < n) {
      off[base + i] = run;
      cur[base + i] = run;
      run += deg[base + i];
    }
  }
}

// ---------------- scatter edges into CSR (+edge->pos map) for both snapshots ----------------
__global__ void scatter_kernel(const int* __restrict__ ei,
                               int* __restrict__ cur0, int* __restrict__ cur1,
                               int* __restrict__ csr0, int* __restrict__ csr1,
                               int* __restrict__ pos0, int* __restrict__ pos1, int e) {
  int i = blockIdx.x * blockDim.x + threadIdx.x;
  if (i < 2 * e) {
    int t = i >= e ? 1 : 0;
    int j = i - t * e;
    int s = ei[(size_t)t * 2 * e + j];
    int d = ei[(size_t)t * 2 * e + e + j];
    int* cur = t ? cur1 : cur0;
    int* csr = t ? csr1 : csr0;
    int* pos = t ? pos1 : pos0;
    int p = atomicAdd(&cur[d], 1);
    csr[p] = s;
    pos[j] = p;
  }
}

// ---------------- fused GEMM + bf16-H write + per-node attention scores (both t) ----------------
template<int M, bool F32IN>
__global__ __launch_bounds__(256) void gemm_kernel(const void* __restrict__ X0v,
                                                   const void* __restrict__ X1v,
                                                   const short* __restrict__ Wt,
                                                   unsigned short* __restrict__ H0,
                                                   unsigned short* __restrict__ H1,
                                                   const float* __restrict__ att,
                                                   float* __restrict__ si0, float* __restrict__ si1,
                                                   float* __restrict__ sj0, float* __restrict__ sj1,
                                                   int nrows) {
  int t = blockIdx.y;
  const void* Xv = t ? X1v : X0v;
  unsigned short* Hbf = t ? H1 : H0;
  float* s_i = t ? si1 : si0;
  float* s_j = t ? sj1 : sj0;

  int wave = blockIdx.x * 4 + (threadIdx.x >> 6);
  int lane = threadIdx.x & 63;
  if (wave * 16 >= nrows) return;
  int m16 = lane & 15, quad = lane >> 4;

  bf16x8 a[4];
  size_t arow = (size_t)(wave * 16 + m16) * K_DIM + quad * 8;
  if constexpr (F32IN) {
    const float* X = (const float*)Xv;
#pragma unroll
    for (int kc = 0; kc < 4; kc++) {
      f32x4 lo = *(const f32x4*)(X + arow + kc * 32);
      f32x4 hi = *(const f32x4*)(X + arow + kc * 32 + 4);
#pragma unroll
      for (int j = 0; j < 4; j++) {
        ((unsigned short*)&a[kc])[j]     = f2bf(lo[j]);
        ((unsigned short*)&a[kc])[4 + j] = f2bf(hi[j]);
      }
    }
  } else {
    const short* X = (const short*)Xv;
#pragma unroll
    for (int kc = 0; kc < 4; kc++) a[kc] = *(const bf16x8*)(X + arow + kc * 32);
  }

  float sip[4] = {0.f, 0.f, 0.f, 0.f}, sjp[4] = {0.f, 0.f, 0.f, 0.f};
#pragma unroll
  for (int nt = 0; nt < M / 16; nt++) {
    f32x4 acc = {0.f, 0.f, 0.f, 0.f};
    size_t brow = (size_t)(nt * 16 + m16) * K_DIM + quad * 8;
#pragma unroll
    for (int kc = 0; kc < 4; kc++) {
      bf16x8 b = *(const bf16x8*)(Wt + brow + kc * 32);
      acc = __builtin_amdgcn_mfma_f32_16x16x32_bf16(a[kc], b, acc, 0, 0, 0);
    }
    int col = nt * 16 + m16;
    float aA = att[col], aB = att[M + col];
#pragma unroll
    for (int r = 0; r < 4; r++) {
      int row = wave * 16 + quad * 4 + r;
      Hbf[(size_t)row * M + col] = f2bf(acc[r]);
      sip[r] += acc[r] * aA;
      sjp[r] += acc[r] * aB;
    }
  }
#pragma unroll
  for (int o = 1; o < 16; o <<= 1) {
#pragma unroll
    for (int r = 0; r < 4; r++) {
      sip[r] += __shfl_xor(sip[r], o);
      sjp[r] += __shfl_xor(sjp[r], o);
    }
  }
  if (m16 == 0) {
#pragma unroll
    for (int r = 0; r < 4; r++) {
      int row = wave * 16 + quad * 4 + r;
      s_i[row] = sip[r];
      s_j[row] = sjp[r];
    }
  }
}

// ---------------- per-edge attention prob p (to CSR order) + skl accumulation (both t) ----------------
__global__ __launch_bounds__(256) void edge_p_kernel(const int* __restrict__ ei,
                                                     const int* __restrict__ pos0, const int* __restrict__ pos1,
                                                     const float* __restrict__ si0, const float* __restrict__ si1,
                                                     const float* __restrict__ sj0, const float* __restrict__ sj1,
                                                     float* __restrict__ w0, float* __restrict__ w1,
                                                     float* __restrict__ accum, int layer_off, int e) {
  int t = blockIdx.y;
  const int* src = ei + (size_t)t * 2 * e;
  const int* dst = src + e;
  const int* pos = t ? pos1 : pos0;
  const float* s_i = t ? si1 : si0;
  const float* s_j = t ? sj1 : sj0;
  float* w_csr = t ? w1 : w0;
  float* skl_accum = accum + layer_off + 2 * t + 1;

  __shared__ float red[4];
  int i = blockIdx.x * blockDim.x + threadIdx.x;
  float skl = 0.f;
  const float q = 1.0f / (1.0f + __expf(-(1.0f / 15.0f)));
  if (i < e) {
    float lg = s_i[dst[i]] + s_j[src[i]];
    lg = lg > 0.f ? lg : 0.2f * lg;          // leaky_relu
    float p = 1.0f / (1.0f + __expf(-lg));   // sigmoid
    p = fminf(fmaxf(p, 0.01f), 0.99f);       // clip
    w_csr[pos[i]] = p;
    skl = p * __logf(p / q) + (1.0f - p) * __logf((1.0f - p) / (1.0f - q));
  }
#pragma unroll
  for (int o = 32; o > 0; o >>= 1) skl += __shfl_xor(skl, o);
  int wid = threadIdx.x >> 6, lane = threadIdx.x & 63;
  if (lane == 0) red[wid] = skl;
  __syncthreads();
  if (threadIdx.x == 0)
    atomicAdd(skl_accum, red[0] + red[1] + red[2] + red[3]);
}

// ---------------- per-node weighted bf16 gather + mu + ixz (both t) ----------------
// 16 B/lane u16x8 loads: M=256 -> 2 edges/load (32 lanes each), M=128 -> 4 edges/load.
// Metadata via wave-uniform (scalar) clamped loads; lane-group select = cndmask on scalars.
template<int M>  // M = 2C
__global__ __launch_bounds__(256) void aggr_kernel(const unsigned short* __restrict__ H0,
                                                   const unsigned short* __restrict__ H1,
                                                   const int* __restrict__ csr0, const int* __restrict__ csr1,
                                                   const int* __restrict__ off0, const int* __restrict__ off1,
                                                   const int* __restrict__ deg0, const int* __restrict__ deg1,
                                                   const float* __restrict__ w0, const float* __restrict__ w1,
                                                   const float* __restrict__ bias,
                                                   float* __restrict__ mu0, float* __restrict__ mu1,
                                                   float* __restrict__ accum, int layer_off, int n) {
  constexpr int C = M / 2;
  constexpr int LPR = M / 8;                 // lanes per row: 32 (M=256) / 16 (M=128)
  constexpr int LOG2LPR = (M == 256) ? 5 : 4;
  constexpr int EPL = 64 / LPR;              // edges per load: 2 / 4
  constexpr int NL = 4;                      // loads in flight per chunk
  constexpr int U = NL * EPL;                // edges per chunk: 8 / 16

  int t = blockIdx.y;
  const unsigned short* Hbf = t ? H1 : H0;
  const int* csr = t ? csr1 : csr0;
  const int* off = t ? off1 : off0;
  const int* deg = t ? deg1 : deg0;
  const float* w = t ? w1 : w0;
  float* mu = t ? mu1 : mu0;
  float* ixz_accum = accum + layer_off + 2 * t;

  __shared__ float red[4];
  int wid = threadIdx.x >> 6, lane = threadIdx.x & 63;
  int wave = blockIdx.x * 4 + wid;
  float ixz = 0.f;

  if (wave < n) {
    int d     = __builtin_amdgcn_readfirstlane(deg[wave]);
    int start = __builtin_amdgcn_readfirstlane(off[wave]);
    float norm = 1.0f / (float)d;
    int sub = lane & (LPR - 1);
    int g   = lane >> LOG2LPR;   // which edge within the load
    int c0  = sub * 8;           // 8 channels per lane

    float acc[8];
#pragma unroll
    for (int k = 0; k < 8; k++) acc[k] = 0.f;

    for (int e0 = 0; e0 < d; e0 += U) {
      u16x8 hv[NL];
      float wt[NL];
#pragma unroll
      for (int l = 0; l < NL; l++) {
        int eb = e0 + l * EPL;
        int idx; float wl;
        if constexpr (EPL == 2) {
          int ia = __builtin_amdgcn_readfirstlane(csr[start + (eb     < d ? eb     : d - 1)]);
          int ib = __builtin_amdgcn_readfirstlane(csr[start + (eb + 1 < d ? eb + 1 : d - 1)]);
          float wa = (eb     < d) ? w[start + eb]     : 0.f;
          float wb = (eb + 1 < d) ? w[start + eb + 1] : 0.f;
          idx = g ? ib : ia;
          wl  = g ? wb : wa;
        } else {
          int i0 = __builtin_amdgcn_readfirstlane(csr[start + (eb     < d ? eb     : d - 1)]);
          int i1 = __builtin_amdgcn_readfirstlane(csr[start + (eb + 1 < d ? eb + 1 : d - 1)]);
          int i2 = __builtin_amdgcn_readfirstlane(csr[start + (eb + 2 < d ? eb + 2 : d - 1)]);
          int i3 = __builtin_amdgcn_readfirstlane(csr[start + (eb + 3 < d ? eb + 3 : d - 1)]);
          float f0 = (eb     < d) ? w[start + eb]     : 0.f;
          float f1 = (eb + 1 < d) ? w[start + eb + 1] : 0.f;
          float f2 = (eb + 2 < d) ? w[start + eb + 2] : 0.f;
          float f3 = (eb + 3 < d) ? w[start + eb + 3] : 0.f;
          int ia = (g & 1) ? i1 : i0;
          int ib = (g & 1) ? i3 : i2;
          idx = (g & 2) ? ib : ia;
          float fa = (g & 1) ? f1 : f0;
          float fb = (g & 1) ? f3 : f2;
          wl = (g & 2) ? fb : fa;
        }
        wt[l] = wl;
        hv[l] = *(const u16x8*)(Hbf + (size_t)idx * M + c0);
      }
      __builtin_amdgcn_sched_barrier(0);  // all NL gathers issued before first use
#pragma unroll
      for (int l = 0; l < NL; l++) {
#pragma unroll
        for (int k = 0; k < 8; k++) acc[k] += wt[l] * bf2f(hv[l][k]);
      }
    }

    // combine lane-groups (same channels, different edges)
#pragma unroll
    for (int o = LPR; o < 64; o <<= 1) {
#pragma unroll
      for (int k = 0; k < 8; k++) acc[k] += __shfl_xor(acc[k], o);
    }

    if (lane < LPR) {
      if (c0 < C) {
        f32x4 m0, m1;
#pragma unroll
        for (int k = 0; k < 4; k++) {
          float a = acc[k] * norm + bias[c0 + k];
          m0[k] = a;
          ixz += 0.5f * a * a - 0.5f;
        }
#pragma unroll
        for (int k = 0; k < 4; k++) {
          float a = acc[4 + k] * norm + bias[c0 + 4 + k];
          m1[k] = a;
          ixz += 0.5f * a * a - 0.5f;
        }
        *(f32x4*)(mu + (size_t)wave * C + c0) = m0;
        *(f32x4*)(mu + (size_t)wave * C + c0 + 4) = m1;
      } else {
#pragma unroll
        for (int k = 0; k < 8; k++) {
          float a = acc[k] * norm + bias[c0 + k];
          float sp = (a > 20.f) ? a : log1pf(__expf(a));  // softplus
          sp += 1e-10f;
          ixz += -__logf(sp) + 0.5f * sp * sp;
        }
      }
    }
  }
#pragma unroll
  for (int o = 32; o > 0; o >>= 1) ixz += __shfl_xor(ixz, o);
  if (lane == 0) red[wid] = ixz;
  __syncthreads();
  if (threadIdx.x == 0)
    atomicAdd(ixz_accum, red[0] + red[1] + red[2] + red[3]);
}

// ---------------- layer-1 temporal fusion + ReLU -> bf16 layer-2 inputs ----------------
__global__ void fuse1_kernel(const float* __restrict__ mu0, const float* __restrict__ mu1,
                             __hip_bfloat16* __restrict__ x0, __hip_bfloat16* __restrict__ x1, int n) {
  int i = blockIdx.x * blockDim.x + threadIdx.x;
  if (i < n) {
    float m0 = mu0[i], m1 = mu1[i];
    x0[i] = __float2bfloat16(fmaxf(m0, 0.f));
    x1[i] = __float2bfloat16(fmaxf(0.4f * m0 + 0.2f * m1, 0.f));
  }
}

// ---------------- layer-2 temporal fusion -> final output (fp32) ----------------
__global__ void fuse2_kernel(const float* __restrict__ mu0, const float* __restrict__ mu1,
                             float* __restrict__ out, int n) {
  int i = blockIdx.x * blockDim.x + threadIdx.x;
  if (i < n) {
    float m0 = mu0[i], m1 = mu1[i];
    out[i] = m0;
    out[n + i] = 0.4f * m0 + 0.2f * m1;
  }
}

// ---------------- scalars ----------------
__global__ void finalize_kernel(const float* __restrict__ accum, float* __restrict__ out2) {
  out2[0] = (accum[0] + accum[2] + accum[4] + accum[6]) / (4.0f * (float)N_NODES);
  out2[1] = (accum[1] + accum[3] + accum[5] + accum[7]) / (4.0f * (float)N_EDGES);
}

extern "C" void kernel_launch(void* const* d_in, const int* in_sizes, int n_in,
                              void* d_out, int out_size, void* d_ws, size_t ws_size,
                              hipStream_t stream) {
  const float* x_all = (const float*)d_in[0];
  const int* ei      = (const int*)d_in[1];
  const float* W1    = (const float*)d_in[2];
  const float* att1  = (const float*)d_in[3];
  const float* b1    = (const float*)d_in[4];
  const float* W2    = (const float*)d_in[5];
  const float* att2  = (const float*)d_in[6];
  const float* b2    = (const float*)d_in[7];
  float* out         = (float*)d_out;

  char* ws = (char*)d_ws;
  size_t off = 0;
  auto alloc = [&](size_t bytes) {
    char* p = ws + off;
    off = (off + bytes + 255) & ~(size_t)255;
    return p;
  };
  unsigned short* wt1  = (unsigned short*)alloc(256 * 128 * sizeof(short));
  unsigned short* wt2  = (unsigned short*)alloc(128 * 128 * sizeof(short));
  unsigned short* hbf0 = (unsigned short*)alloc((size_t)N_NODES * 256 * sizeof(short));
  unsigned short* hbf1 = (unsigned short*)alloc((size_t)N_NODES * 256 * sizeof(short));
  float* si0   = (float*)alloc(N_NODES * sizeof(float));
  float* si1   = (float*)alloc(N_NODES * sizeof(float));
  float* sj0   = (float*)alloc(N_NODES * sizeof(float));
  float* sj1   = (float*)alloc(N_NODES * sizeof(float));
  float* mu1_0 = (float*)alloc((size_t)N_NODES * 128 * sizeof(float));
  float* mu1_1 = (float*)alloc((size_t)N_NODES * 128 * sizeof(float));
  __hip_bfloat16* x2_0 = (__hip_bfloat16*)alloc((size_t)N_NODES * 128 * sizeof(short));
  __hip_bfloat16* x2_1 = (__hip_bfloat16*)alloc((size_t)N_NODES * 128 * sizeof(short));
  // mu2 buffers alias mu1_0's region (mu1 dead after fuse1; stream-ordered)
  float* mu2_0 = mu1_0;
  float* mu2_1 = mu1_0 + (size_t)N_NODES * 64;
  int* degp[2]  = {(int*)alloc(N_NODES * 4), (int*)alloc(N_NODES * 4)};
  int* offp[2]  = {(int*)alloc(N_NODES * 4), (int*)alloc(N_NODES * 4)};
  int* curp[2]  = {(int*)alloc(N_NODES * 4), (int*)alloc(N_NODES * 4)};
  int* csrp[2]  = {(int*)alloc(N_EDGES * 4), (int*)alloc(N_EDGES * 4)};
  int* posp[2]  = {(int*)alloc(N_EDGES * 4), (int*)alloc(N_EDGES * 4)};
  float* wc0    = (float*)alloc(N_EDGES * 4);
  float* wc1    = (float*)alloc(N_EDGES * 4);
  float* accum  = (float*)alloc(8 * sizeof(float));

  hipMemsetAsync(degp[0], 0, N_NODES * 4, stream);
  hipMemsetAsync(degp[1], 0, N_NODES * 4, stream);
  hipMemsetAsync(accum, 0, 8 * sizeof(float), stream);

  transpose_w_kernel<<<192, 256, 0, stream>>>(W1, wt1, W2, wt2);

  deg_kernel<<<(2 * N_EDGES + 255) / 256, 256, 0, stream>>>(ei, degp[0], degp[1], N_EDGES);
  scan_kernel<<<2, 1024, 0, stream>>>(degp[0], offp[0], curp[0], degp[1], offp[1], curp[1], N_NODES);
  scatter_kernel<<<(2 * N_EDGES + 255) / 256, 256, 0, stream>>>(ei, curp[0], curp[1],
                                                                csrp[0], csrp[1],
                                                                posp[0], posp[1], N_EDGES);

  dim3 ggrid(469, 2), egrid((N_EDGES + 255) / 256, 2), agrid(7500, 2);

  // ---- layer 1 (C = 128, M = 256) ----
  const float* x0 = x_all;
  const float* x1 = x_all + (size_t)N_NODES * K_DIM;
  gemm_kernel<256, true><<<ggrid, 256, 0, stream>>>(x0, x1, (const short*)wt1, hbf0, hbf1,
                                                    att1, si0, si1, sj0, sj1, N_NODES);
  edge_p_kernel<<<egrid, 256, 0, stream>>>(ei, posp[0], posp[1], si0, si1, sj0, sj1,
                                           wc0, wc1, accum, 0, N_EDGES);
  aggr_kernel<256><<<agrid, 256, 0, stream>>>(hbf0, hbf1, csrp[0], csrp[1], offp[0], offp[1],
                                              degp[0], degp[1], wc0, wc1, b1,
                                              mu1_0, mu1_1, accum, 0, N_NODES);
  fuse1_kernel<<<(N_NODES * 128 + 255) / 256, 256, 0, stream>>>(mu1_0, mu1_1, x2_0, x2_1, N_NODES * 128);

  // ---- layer 2 (C = 64, M = 128) ----
  gemm_kernel<128, false><<<ggrid, 256, 0, stream>>>(x2_0, x2_1, (const short*)wt2, hbf0, hbf1,
                                                     att2, si0, si1, sj0, sj1, N_NODES);
  edge_p_kernel<<<egrid, 256, 0, stream>>>(ei, posp[0], posp[1], si0, si1, sj0, sj1,
                                           wc0, wc1, accum, 4, N_EDGES);
  aggr_kernel<128><<<agrid, 256, 0, stream>>>(hbf0, hbf1, csrp[0], csrp[1], offp[0], offp[1],
                                              degp[0], degp[1], wc0, wc1, b2,
                                              mu2_0, mu2_1, accum, 4, N_NODES);
  fuse2_kernel<<<(N_NODES * 64 + 255) / 256, 256, 0, stream>>>(mu2_0, mu2_1, out, N_NODES * 64);
  finalize_kernel<<<1, 1, 0, stream>>>(accum, out + (size_t)2 * N_NODES * 64);
}

// Round 9
// 840.684 us; speedup vs baseline: 1.0270x; 1.0270x over previous
//
#include <hip/hip_runtime.h>
#include <hip/hip_bf16.h>
#include <hip/hip_fp8.h>

#define N_NODES 30000
#define N_EDGES 510000
#define K_DIM   128

typedef short bf16x8 __attribute__((ext_vector_type(8)));
typedef float f32x4  __attribute__((ext_vector_type(4)));
typedef float f32x2  __attribute__((ext_vector_type(2)));

__device__ __forceinline__ unsigned short f2bf(float f) {
  __hip_bfloat16 h = __float2bfloat16(f);
  return *(unsigned short*)&h;
}
__device__ __forceinline__ unsigned char f2fp8(float f) {
  __hip_fp8_e4m3 q(f);
  return (unsigned char)q.__x;
}
__device__ __forceinline__ float fp82f(unsigned char u) {
  __hip_fp8_e4m3 q;
  q.__x = (__hip_fp8_storage_t)u;
  return (float)q;
}

// ---------------- both W transposes (K x M fp32) -> (M x K bf16) ----------------
__global__ void transpose_w_kernel(const float* __restrict__ W1, unsigned short* __restrict__ Wt1,
                                   const float* __restrict__ W2, unsigned short* __restrict__ Wt2) {
  int i = blockIdx.x * blockDim.x + threadIdx.x;
  if (i < 128 * 256) {
    int k = i >> 8, m = i & 255;
    Wt1[m * 128 + k] = f2bf(W1[i]);
  } else if (i < 128 * 256 + 128 * 128) {
    int j = i - 128 * 256;
    int k = j >> 7, m = j & 127;
    Wt2[m * 128 + k] = f2bf(W2[j]);
  }
}

// ---------------- degree for both snapshots ----------------
__global__ void deg_kernel(const int* __restrict__ ei, int* __restrict__ deg0,
                           int* __restrict__ deg1, int e) {
  int i = blockIdx.x * blockDim.x + threadIdx.x;
  if (i < 2 * e) {
    int t = i >= e ? 1 : 0;
    int j = i - t * e;
    int d = ei[(size_t)t * 2 * e + e + j];
    atomicAdd(&(t ? deg1 : deg0)[d], 1);
  }
}

// ---------------- exclusive scan (3-phase), one block per snapshot ----------------
__global__ __launch_bounds__(1024) void scan_kernel(const int* __restrict__ deg0, int* __restrict__ off0, int* __restrict__ cur0,
                                                    const int* __restrict__ deg1, int* __restrict__ off1, int* __restrict__ cur1,
                                                    int n) {
  const int* deg = blockIdx.x ? deg1 : deg0;
  int* off = blockIdx.x ? off1 : off0;
  int* cur = blockIdx.x ? cur1 : cur0;
  const int CHUNK = 30;  // 1024*30 >= 30000
  __shared__ int wsum[16];
  int tid = threadIdx.x;
  int base = tid * CHUNK;
  int sum = 0;
  for (int i = 0; i < CHUNK; i++)
    if (base + i < n) sum += deg[base + i];
  int lane = tid & 63, wid = tid >> 6;
  int incl = sum;
#pragma unroll
  for (int o = 1; o < 64; o <<= 1) {
    int v = __shfl_up(incl, o);
    if (lane >= o) incl += v;
  }
  if (lane == 63) wsum[wid] = incl;
  __syncthreads();
  if (tid == 0) {
    int run = 0;
    for (int w = 0; w < 16; w++) { int v = wsum[w]; wsum[w] = run; run += v; }
  }
  __syncthreads();
  int run = incl - sum + wsum[wid];
  for (int i = 0; i < CHUNK; i++) {
    if (base + i < n) {
      off[base + i] = run;
      cur[base + i] = run;
      run += deg[base + i];
    }
  }
}

// ---------------- scatter edges into CSR (+edge->pos map) for both snapshots ----------------
__global__ void scatter_kernel(const int* __restrict__ ei,
                               int* __restrict__ cur0, int* __restrict__ cur1,
                               int* __restrict__ csr0, int* __restrict__ csr1,
                               int* __restrict__ pos0, int* __restrict__ pos1, int e) {
  int i = blockIdx.x * blockDim.x + threadIdx.x;
  if (i < 2 * e) {
    int t = i >= e ? 1 : 0;
    int j = i - t * e;
    int s = ei[(size_t)t * 2 * e + j];
    int d = ei[(size_t)t * 2 * e + e + j];
    int* cur = t ? cur1 : cur0;
    int* csr = t ? csr1 : csr0;
    int* pos = t ? pos1 : pos0;
    int p = atomicAdd(&cur[d], 1);
    csr[p] = s;
    pos[j] = p;
  }
}

// ---------------- fused GEMM + fp8-H write + per-node attention scores (both t) ----------------
template<int M, bool F32IN>
__global__ __launch_bounds__(256) void gemm_kernel(const void* __restrict__ X0v,
                                                   const void* __restrict__ X1v,
                                                   const short* __restrict__ Wt,
                                                   unsigned char* __restrict__ H0,
                                                   unsigned char* __restrict__ H1,
                                                   const float* __restrict__ att,
                                                   float* __restrict__ si0, float* __restrict__ si1,
                                                   float* __restrict__ sj0, float* __restrict__ sj1,
                                                   int nrows) {
  int t = blockIdx.y;
  const void* Xv = t ? X1v : X0v;
  unsigned char* Hf8 = t ? H1 : H0;
  float* s_i = t ? si1 : si0;
  float* s_j = t ? sj1 : sj0;

  int wave = blockIdx.x * 4 + (threadIdx.x >> 6);
  int lane = threadIdx.x & 63;
  if (wave * 16 >= nrows) return;
  int m16 = lane & 15, quad = lane >> 4;

  bf16x8 a[4];
  size_t arow = (size_t)(wave * 16 + m16) * K_DIM + quad * 8;
  if constexpr (F32IN) {
    const float* X = (const float*)Xv;
#pragma unroll
    for (int kc = 0; kc < 4; kc++) {
      f32x4 lo = *(const f32x4*)(X + arow + kc * 32);
      f32x4 hi = *(const f32x4*)(X + arow + kc * 32 + 4);
#pragma unroll
      for (int j = 0; j < 4; j++) {
        ((unsigned short*)&a[kc])[j]     = f2bf(lo[j]);
        ((unsigned short*)&a[kc])[4 + j] = f2bf(hi[j]);
      }
    }
  } else {
    const short* X = (const short*)Xv;
#pragma unroll
    for (int kc = 0; kc < 4; kc++) a[kc] = *(const bf16x8*)(X + arow + kc * 32);
  }

  float sip[4] = {0.f, 0.f, 0.f, 0.f}, sjp[4] = {0.f, 0.f, 0.f, 0.f};
#pragma unroll
  for (int nt = 0; nt < M / 16; nt++) {
    f32x4 acc = {0.f, 0.f, 0.f, 0.f};
    size_t brow = (size_t)(nt * 16 + m16) * K_DIM + quad * 8;
#pragma unroll
    for (int kc = 0; kc < 4; kc++) {
      bf16x8 b = *(const bf16x8*)(Wt + brow + kc * 32);
      acc = __builtin_amdgcn_mfma_f32_16x16x32_bf16(a[kc], b, acc, 0, 0, 0);
    }
    int col = nt * 16 + m16;
    float aA = att[col], aB = att[M + col];
#pragma unroll
    for (int r = 0; r < 4; r++) {
      int row = wave * 16 + quad * 4 + r;
      Hf8[(size_t)row * M + col] = f2fp8(acc[r]);
      sip[r] += acc[r] * aA;
      sjp[r] += acc[r] * aB;
    }
  }
#pragma unroll
  for (int o = 1; o < 16; o <<= 1) {
#pragma unroll
    for (int r = 0; r < 4; r++) {
      sip[r] += __shfl_xor(sip[r], o);
      sjp[r] += __shfl_xor(sjp[r], o);
    }
  }
  if (m16 == 0) {
#pragma unroll
    for (int r = 0; r < 4; r++) {
      int row = wave * 16 + quad * 4 + r;
      s_i[row] = sip[r];
      s_j[row] = sjp[r];
    }
  }
}

// ---------------- per-edge attention prob p (to CSR order) + skl accumulation (both t) ----------------
__global__ __launch_bounds__(256) void edge_p_kernel(const int* __restrict__ ei,
                                                     const int* __restrict__ pos0, const int* __restrict__ pos1,
                                                     const float* __restrict__ si0, const float* __restrict__ si1,
                                                     const float* __restrict__ sj0, const float* __restrict__ sj1,
                                                     float* __restrict__ w0, float* __restrict__ w1,
                                                     float* __restrict__ accum, int layer_off, int e) {
  int t = blockIdx.y;
  const int* src = ei + (size_t)t * 2 * e;
  const int* dst = src + e;
  const int* pos = t ? pos1 : pos0;
  const float* s_i = t ? si1 : si0;
  const float* s_j = t ? sj1 : sj0;
  float* w_csr = t ? w1 : w0;
  float* skl_accum = accum + layer_off + 2 * t + 1;

  __shared__ float red[4];
  int i = blockIdx.x * blockDim.x + threadIdx.x;
  float skl = 0.f;
  const float q = 1.0f / (1.0f + __expf(-(1.0f / 15.0f)));
  if (i < e) {
    float lg = s_i[dst[i]] + s_j[src[i]];
    lg = lg > 0.f ? lg : 0.2f * lg;          // leaky_relu
    float p = 1.0f / (1.0f + __expf(-lg));   // sigmoid
    p = fminf(fmaxf(p, 0.01f), 0.99f);       // clip
    w_csr[pos[i]] = p;
    skl = p * __logf(p / q) + (1.0f - p) * __logf((1.0f - p) / (1.0f - q));
  }
#pragma unroll
  for (int o = 32; o > 0; o >>= 1) skl += __shfl_xor(skl, o);
  int wid = threadIdx.x >> 6, lane = threadIdx.x & 63;
  if (lane == 0) red[wid] = skl;
  __syncthreads();
  if (threadIdx.x == 0)
    atomicAdd(skl_accum, red[0] + red[1] + red[2] + red[3]);
}

// ---------------- per-node weighted fp8 gather + mu + ixz (both t) ----------------
// Round-5 structure, fp8 rows: M=256 -> 4 B/lane (dword), M=128 -> 2 B/lane.
template<int M>  // M = 2C
__global__ __launch_bounds__(256) void aggr_kernel(const unsigned char* __restrict__ H0,
                                                   const unsigned char* __restrict__ H1,
                                                   const int* __restrict__ csr0, const int* __restrict__ csr1,
                                                   const int* __restrict__ off0, const int* __restrict__ off1,
                                                   const int* __restrict__ deg0, const int* __restrict__ deg1,
                                                   const float* __restrict__ w0, const float* __restrict__ w1,
                                                   const float* __restrict__ bias,
                                                   float* __restrict__ mu0, float* __restrict__ mu1,
                                                   float* __restrict__ accum, int layer_off, int n) {
  constexpr int C = M / 2;
  constexpr int V = M / 64;   // fp8 bytes (channels) per lane: 4 or 2
  constexpr int U = 8;        // 8 independent row-gathers in flight

  int t = blockIdx.y;
  const unsigned char* Hf8 = t ? H1 : H0;
  const int* csr = t ? csr1 : csr0;
  const int* off = t ? off1 : off0;
  const int* deg = t ? deg1 : deg0;
  const float* w = t ? w1 : w0;
  float* mu = t ? mu1 : mu0;
  float* ixz_accum = accum + layer_off + 2 * t;

  __shared__ float red[4];
  int wid = threadIdx.x >> 6, lane = threadIdx.x & 63;
  int wave = blockIdx.x * 4 + wid;
  float ixz = 0.f;

  if (wave < n) {
    int d     = __builtin_amdgcn_readfirstlane(deg[wave]);
    int start = __builtin_amdgcn_readfirstlane(off[wave]);
    float norm = 1.0f / (float)d;
    int c0 = lane * V;

    float acc[V];
#pragma unroll
    for (int k = 0; k < V; k++) acc[k] = 0.f;

    for (int e0 = 0; e0 < d; e0 += U) {
      int idxs[U];
      float ws[U];
#pragma unroll
      for (int u = 0; u < U; u++) {
        int ee = e0 + u;
        int ap = start + (ee < d ? ee : 0);  // clamped, always-valid address
        idxs[u] = csr[ap];
        ws[u]   = (ee < d) ? w[ap] : 0.f;
      }
      unsigned int hv[U];
#pragma unroll
      for (int u = 0; u < U; u++) {
        if constexpr (V == 4)
          hv[u] = *(const unsigned int*)(Hf8 + (size_t)idxs[u] * M + c0);
        else
          hv[u] = (unsigned int)*(const unsigned short*)(Hf8 + (size_t)idxs[u] * M + c0);
      }
      __builtin_amdgcn_sched_barrier(0);  // all U gathers issued before first use
#pragma unroll
      for (int u = 0; u < U; u++) {
#pragma unroll
        for (int k = 0; k < V; k++)
          acc[k] += ws[u] * fp82f((unsigned char)(hv[u] >> (8 * k)));
      }
    }

    if (c0 < C) {
#pragma unroll
      for (int k = 0; k < V; k++) {
        float a = acc[k] * norm + bias[c0 + k];
        acc[k] = a;
        ixz += 0.5f * a * a - 0.5f;
      }
      if constexpr (V == 4)
        *(f32x4*)(mu + (size_t)wave * C + c0) = *(f32x4*)acc;
      else
        *(f32x2*)(mu + (size_t)wave * C + c0) = *(f32x2*)acc;
    } else {
#pragma unroll
      for (int k = 0; k < V; k++) {
        float a = acc[k] * norm + bias[c0 + k];
        float sp = (a > 20.f) ? a : log1pf(__expf(a));  // softplus
        sp += 1e-10f;
        ixz += -__logf(sp) + 0.5f * sp * sp;
      }
    }
  }
#pragma unroll
  for (int o = 32; o > 0; o >>= 1) ixz += __shfl_xor(ixz, o);
  if (lane == 0) red[wid] = ixz;
  __syncthreads();
  if (threadIdx.x == 0)
    atomicAdd(ixz_accum, red[0] + red[1] + red[2] + red[3]);
}

// ---------------- layer-1 temporal fusion + ReLU -> bf16 layer-2 inputs ----------------
__global__ void fuse1_kernel(const float* __restrict__ mu0, const float* __restrict__ mu1,
                             __hip_bfloat16* __restrict__ x0, __hip_bfloat16* __restrict__ x1, int n) {
  int i = blockIdx.x * blockDim.x + threadIdx.x;
  if (i < n) {
    float m0 = mu0[i], m1 = mu1[i];
    x0[i] = __float2bfloat16(fmaxf(m0, 0.f));
    x1[i] = __float2bfloat16(fmaxf(0.4f * m0 + 0.2f * m1, 0.f));
  }
}

// ---------------- layer-2 temporal fusion -> final output (fp32) ----------------
__global__ void fuse2_kernel(const float* __restrict__ mu0, const float* __restrict__ mu1,
                             float* __restrict__ out, int n) {
  int i = blockIdx.x * blockDim.x + threadIdx.x;
  if (i < n) {
    float m0 = mu0[i], m1 = mu1[i];
    out[i] = m0;
    out[n + i] = 0.4f * m0 + 0.2f * m1;
  }
}

// ---------------- scalars ----------------
__global__ void finalize_kernel(const float* __restrict__ accum, float* __restrict__ out2) {
  out2[0] = (accum[0] + accum[2] + accum[4] + accum[6]) / (4.0f * (float)N_NODES);
  out2[1] = (accum[1] + accum[3] + accum[5] + accum[7]) / (4.0f * (float)N_EDGES);
}

extern "C" void kernel_launch(void* const* d_in, const int* in_sizes, int n_in,
                              void* d_out, int out_size, void* d_ws, size_t ws_size,
                              hipStream_t stream) {
  const float* x_all = (const float*)d_in[0];
  const int* ei      = (const int*)d_in[1];
  const float* W1    = (const float*)d_in[2];
  const float* att1  = (const float*)d_in[3];
  const float* b1    = (const float*)d_in[4];
  const float* W2    = (const float*)d_in[5];
  const float* att2  = (const float*)d_in[6];
  const float* b2    = (const float*)d_in[7];
  float* out         = (float*)d_out;

  char* ws = (char*)d_ws;
  size_t off = 0;
  auto alloc = [&](size_t bytes) {
    char* p = ws + off;
    off = (off + bytes + 255) & ~(size_t)255;
    return p;
  };
  unsigned short* wt1  = (unsigned short*)alloc(256 * 128 * sizeof(short));
  unsigned short* wt2  = (unsigned short*)alloc(128 * 128 * sizeof(short));
  unsigned char* hf8_0 = (unsigned char*)alloc((size_t)N_NODES * 256);
  unsigned char* hf8_1 = (unsigned char*)alloc((size_t)N_NODES * 256);
  float* si0   = (float*)alloc(N_NODES * sizeof(float));
  float* si1   = (float*)alloc(N_NODES * sizeof(float));
  float* sj0   = (float*)alloc(N_NODES * sizeof(float));
  float* sj1   = (float*)alloc(N_NODES * sizeof(float));
  float* mu1_0 = (float*)alloc((size_t)N_NODES * 128 * sizeof(float));
  float* mu1_1 = (float*)alloc((size_t)N_NODES * 128 * sizeof(float));
  __hip_bfloat16* x2_0 = (__hip_bfloat16*)alloc((size_t)N_NODES * 128 * sizeof(short));
  __hip_bfloat16* x2_1 = (__hip_bfloat16*)alloc((size_t)N_NODES * 128 * sizeof(short));
  // mu2 buffers alias mu1_0's region (mu1 dead after fuse1; stream-ordered)
  float* mu2_0 = mu1_0;
  float* mu2_1 = mu1_0 + (size_t)N_NODES * 64;
  int* degp[2]  = {(int*)alloc(N_NODES * 4), (int*)alloc(N_NODES * 4)};
  int* offp[2]  = {(int*)alloc(N_NODES * 4), (int*)alloc(N_NODES * 4)};
  int* curp[2]  = {(int*)alloc(N_NODES * 4), (int*)alloc(N_NODES * 4)};
  int* csrp[2]  = {(int*)alloc(N_EDGES * 4), (int*)alloc(N_EDGES * 4)};
  int* posp[2]  = {(int*)alloc(N_EDGES * 4), (int*)alloc(N_EDGES * 4)};
  float* wc0    = (float*)alloc(N_EDGES * 4);
  float* wc1    = (float*)alloc(N_EDGES * 4);
  float* accum  = (float*)alloc(8 * sizeof(float));

  hipMemsetAsync(degp[0], 0, N_NODES * 4, stream);
  hipMemsetAsync(degp[1], 0, N_NODES * 4, stream);
  hipMemsetAsync(accum, 0, 8 * sizeof(float), stream);

  transpose_w_kernel<<<192, 256, 0, stream>>>(W1, wt1, W2, wt2);

  deg_kernel<<<(2 * N_EDGES + 255) / 256, 256, 0, stream>>>(ei, degp[0], degp[1], N_EDGES);
  scan_kernel<<<2, 1024, 0, stream>>>(degp[0], offp[0], curp[0], degp[1], offp[1], curp[1], N_NODES);
  scatter_kernel<<<(2 * N_EDGES + 255) / 256, 256, 0, stream>>>(ei, curp[0], curp[1],
                                                                csrp[0], csrp[1],
                                                                posp[0], posp[1], N_EDGES);

  dim3 ggrid(469, 2), egrid((N_EDGES + 255) / 256, 2), agrid(7500, 2);

  // ---- layer 1 (C = 128, M = 256) ----
  const float* x0 = x_all;
  const float* x1 = x_all + (size_t)N_NODES * K_DIM;
  gemm_kernel<256, true><<<ggrid, 256, 0, stream>>>(x0, x1, (const short*)wt1, hf8_0, hf8_1,
                                                    att1, si0, si1, sj0, sj1, N_NODES);
  edge_p_kernel<<<egrid, 256, 0, stream>>>(ei, posp[0], posp[1], si0, si1, sj0, sj1,
                                           wc0, wc1, accum, 0, N_EDGES);
  aggr_kernel<256><<<agrid, 256, 0, stream>>>(hf8_0, hf8_1, csrp[0], csrp[1], offp[0], offp[1],
                                              degp[0], degp[1], wc0, wc1, b1,
                                              mu1_0, mu1_1, accum, 0, N_NODES);
  fuse1_kernel<<<(N_NODES * 128 + 255) / 256, 256, 0, stream>>>(mu1_0, mu1_1, x2_0, x2_1, N_NODES * 128);

  // ---- layer 2 (C = 64, M = 128) ----
  gemm_kernel<128, false><<<ggrid, 256, 0, stream>>>(x2_0, x2_1, (const short*)wt2, hf8_0, hf8_1,
                                                     att2, si0, si1, sj0, sj1, N_NODES);
  edge_p_kernel<<<egrid, 256, 0, stream>>>(ei, posp[0], posp[1], si0, si1, sj0, sj1,
                                           wc0, wc1, accum, 4, N_EDGES);
  aggr_kernel<128><<<agrid, 256, 0, stream>>>(hf8_0, hf8_1, csrp[0], csrp[1], offp[0], offp[1],
                                              degp[0], degp[1], wc0, wc1, b2,
                                              mu2_0, mu2_1, accum, 4, N_NODES);
  fuse2_kernel<<<(N_NODES * 64 + 255) / 256, 256, 0, stream>>>(mu2_0, mu2_1, out, N_NODES * 64);
  finalize_kernel<<<1, 1, 0, stream>>>(accum, out + (size_t)2 * N_NODES * 64);
}

// Round 10
// 837.830 us; speedup vs baseline: 1.0305x; 1.0034x over previous
//
#include <hip/hip_runtime.h>
#include <hip/hip_bf16.h>
#include <hip/hip_fp8.h>

#define N_NODES 30000
#define N_EDGES 510000
#define K_DIM   128

typedef short bf16x8 __attribute__((ext_vector_type(8)));
typedef float f32x4  __attribute__((ext_vector_type(4)));
typedef float f32x2  __attribute__((ext_vector_type(2)));

__device__ __forceinline__ unsigned short f2bf(float f) {
  __hip_bfloat16 h = __float2bfloat16(f);
  return *(unsigned short*)&h;
}
__device__ __forceinline__ unsigned char f2fp8(float f) {
  __hip_fp8_e4m3 q(f);
  return (unsigned char)q.__x;
}
__device__ __forceinline__ float fp82f(unsigned char u) {
  __hip_fp8_e4m3 q;
  q.__x = (__hip_fp8_storage_t)u;
  return (float)q;
}

// ---------------- both W transposes (K x M fp32) -> (M x K bf16) ----------------
__global__ void transpose_w_kernel(const float* __restrict__ W1, unsigned short* __restrict__ Wt1,
                                   const float* __restrict__ W2, unsigned short* __restrict__ Wt2) {
  int i = blockIdx.x * blockDim.x + threadIdx.x;
  if (i < 128 * 256) {
    int k = i >> 8, m = i & 255;
    Wt1[m * 128 + k] = f2bf(W1[i]);
  } else if (i < 128 * 256 + 128 * 128) {
    int j = i - 128 * 256;
    int k = j >> 7, m = j & 127;
    Wt2[m * 128 + k] = f2bf(W2[j]);
  }
}

// ---------------- degree for both snapshots ----------------
__global__ void deg_kernel(const int* __restrict__ ei, int* __restrict__ deg0,
                           int* __restrict__ deg1, int e) {
  int i = blockIdx.x * blockDim.x + threadIdx.x;
  if (i < 2 * e) {
    int t = i >= e ? 1 : 0;
    int j = i - t * e;
    int d = ei[(size_t)t * 2 * e + e + j];
    atomicAdd(&(t ? deg1 : deg0)[d], 1);
  }
}

// ---------------- exclusive scan (3-phase), one block per snapshot ----------------
__global__ __launch_bounds__(1024) void scan_kernel(const int* __restrict__ deg0, int* __restrict__ off0, int* __restrict__ cur0,
                                                    const int* __restrict__ deg1, int* __restrict__ off1, int* __restrict__ cur1,
                                                    int n) {
  const int* deg = blockIdx.x ? deg1 : deg0;
  int* off = blockIdx.x ? off1 : off0;
  int* cur = blockIdx.x ? cur1 : cur0;
  const int CHUNK = 30;  // 1024*30 >= 30000
  __shared__ int wsum[16];
  int tid = threadIdx.x;
  int base = tid * CHUNK;
  int sum = 0;
  for (int i = 0; i < CHUNK; i++)
    if (base + i < n) sum += deg[base + i];
  int lane = tid & 63, wid = tid >> 6;
  int incl = sum;
#pragma unroll
  for (int o = 1; o < 64; o <<= 1) {
    int v = __shfl_up(incl, o);
    if (lane >= o) incl += v;
  }
  if (lane == 63) wsum[wid] = incl;
  __syncthreads();
  if (tid == 0) {
    int run = 0;
    for (int w = 0; w < 16; w++) { int v = wsum[w]; wsum[w] = run; run += v; }
  }
  __syncthreads();
  int run = incl - sum + wsum[wid];
  for (int i = 0; i < CHUNK; i++) {
    if (base + i < n) {
      off[base + i] = run;
      cur[base + i] = run;
      run += deg[base + i];
    }
  }
}

// ---------------- scatter edges into CSR (+pos->dst map) for both snapshots ----------------
__global__ void scatter_kernel(const int* __restrict__ ei,
                               int* __restrict__ cur0, int* __restrict__ cur1,
                               int* __restrict__ csr0, int* __restrict__ csr1,
                               int* __restrict__ dstc0, int* __restrict__ dstc1, int e) {
  int i = blockIdx.x * blockDim.x + threadIdx.x;
  if (i < 2 * e) {
    int t = i >= e ? 1 : 0;
    int j = i - t * e;
    int s = ei[(size_t)t * 2 * e + j];
    int d = ei[(size_t)t * 2 * e + e + j];
    int* cur = t ? cur1 : cur0;
    int* csr = t ? csr1 : csr0;
    int* dstc = t ? dstc1 : dstc0;
    int p = atomicAdd(&cur[d], 1);
    csr[p] = s;
    dstc[p] = d;
  }
}

// ---------------- fused GEMM + fp8-H write + per-node attention scores (both t) ----------------
template<int M, bool F32IN>
__global__ __launch_bounds__(256) void gemm_kernel(const void* __restrict__ X0v,
                                                   const void* __restrict__ X1v,
                                                   const short* __restrict__ Wt,
                                                   unsigned char* __restrict__ H0,
                                                   unsigned char* __restrict__ H1,
                                                   const float* __restrict__ att,
                                                   float* __restrict__ si0, float* __restrict__ si1,
                                                   float* __restrict__ sj0, float* __restrict__ sj1,
                                                   int nrows) {
  int t = blockIdx.y;
  const void* Xv = t ? X1v : X0v;
  unsigned char* Hf8 = t ? H1 : H0;
  float* s_i = t ? si1 : si0;
  float* s_j = t ? sj1 : sj0;

  int wave = blockIdx.x * 4 + (threadIdx.x >> 6);
  int lane = threadIdx.x & 63;
  if (wave * 16 >= nrows) return;
  int m16 = lane & 15, quad = lane >> 4;

  bf16x8 a[4];
  size_t arow = (size_t)(wave * 16 + m16) * K_DIM + quad * 8;
  if constexpr (F32IN) {
    const float* X = (const float*)Xv;
#pragma unroll
    for (int kc = 0; kc < 4; kc++) {
      f32x4 lo = *(const f32x4*)(X + arow + kc * 32);
      f32x4 hi = *(const f32x4*)(X + arow + kc * 32 + 4);
#pragma unroll
      for (int j = 0; j < 4; j++) {
        ((unsigned short*)&a[kc])[j]     = f2bf(lo[j]);
        ((unsigned short*)&a[kc])[4 + j] = f2bf(hi[j]);
      }
    }
  } else {
    const short* X = (const short*)Xv;
#pragma unroll
    for (int kc = 0; kc < 4; kc++) a[kc] = *(const bf16x8*)(X + arow + kc * 32);
  }

  float sip[4] = {0.f, 0.f, 0.f, 0.f}, sjp[4] = {0.f, 0.f, 0.f, 0.f};
#pragma unroll
  for (int nt = 0; nt < M / 16; nt++) {
    f32x4 acc = {0.f, 0.f, 0.f, 0.f};
    size_t brow = (size_t)(nt * 16 + m16) * K_DIM + quad * 8;
#pragma unroll
    for (int kc = 0; kc < 4; kc++) {
      bf16x8 b = *(const bf16x8*)(Wt + brow + kc * 32);
      acc = __builtin_amdgcn_mfma_f32_16x16x32_bf16(a[kc], b, acc, 0, 0, 0);
    }
    int col = nt * 16 + m16;
    float aA = att[col], aB = att[M + col];
#pragma unroll
    for (int r = 0; r < 4; r++) {
      int row = wave * 16 + quad * 4 + r;
      Hf8[(size_t)row * M + col] = f2fp8(acc[r]);
      sip[r] += acc[r] * aA;
      sjp[r] += acc[r] * aB;
    }
  }
#pragma unroll
  for (int o = 1; o < 16; o <<= 1) {
#pragma unroll
    for (int r = 0; r < 4; r++) {
      sip[r] += __shfl_xor(sip[r], o);
      sjp[r] += __shfl_xor(sjp[r], o);
    }
  }
  if (m16 == 0) {
#pragma unroll
    for (int r = 0; r < 4; r++) {
      int row = wave * 16 + quad * 4 + r;
      s_i[row] = sip[r];
      s_j[row] = sjp[r];
    }
  }
}

// ---------------- per-edge attention prob p, CSR order (both t) ----------------
// csr/dstc/w all sequential; s_i[dst] nearly-sequential (CSR is dst-sorted);
// only s_j[src] is a random 4B gather.
__global__ __launch_bounds__(256) void edge_p_kernel(const int* __restrict__ csr0, const int* __restrict__ csr1,
                                                     const int* __restrict__ dstc0, const int* __restrict__ dstc1,
                                                     const float* __restrict__ si0, const float* __restrict__ si1,
                                                     const float* __restrict__ sj0, const float* __restrict__ sj1,
                                                     float* __restrict__ w0, float* __restrict__ w1,
                                                     float* __restrict__ accum, int layer_off, int e) {
  int t = blockIdx.y;
  const int* csr = t ? csr1 : csr0;
  const int* dstc = t ? dstc1 : dstc0;
  const float* s_i = t ? si1 : si0;
  const float* s_j = t ? sj1 : sj0;
  float* w_csr = t ? w1 : w0;
  float* skl_accum = accum + layer_off + 2 * t + 1;

  __shared__ float red[4];
  int i = blockIdx.x * blockDim.x + threadIdx.x;
  float skl = 0.f;
  const float q = 1.0f / (1.0f + __expf(-(1.0f / 15.0f)));
  if (i < e) {
    float lg = s_i[dstc[i]] + s_j[csr[i]];
    lg = lg > 0.f ? lg : 0.2f * lg;          // leaky_relu
    float p = 1.0f / (1.0f + __expf(-lg));   // sigmoid
    p = fminf(fmaxf(p, 0.01f), 0.99f);       // clip
    w_csr[i] = p;
    skl = p * __logf(p / q) + (1.0f - p) * __logf((1.0f - p) / (1.0f - q));
  }
#pragma unroll
  for (int o = 32; o > 0; o >>= 1) skl += __shfl_xor(skl, o);
  int wid = threadIdx.x >> 6, lane = threadIdx.x & 63;
  if (lane == 0) red[wid] = skl;
  __syncthreads();
  if (threadIdx.x == 0)
    atomicAdd(skl_accum, red[0] + red[1] + red[2] + red[3]);
}

// ---------------- per-node weighted fp8 gather + mu + ixz (both t) ----------------
template<int M>  // M = 2C
__global__ __launch_bounds__(256) void aggr_kernel(const unsigned char* __restrict__ H0,
                                                   const unsigned char* __restrict__ H1,
                                                   const int* __restrict__ csr0, const int* __restrict__ csr1,
                                                   const int* __restrict__ off0, const int* __restrict__ off1,
                                                   const int* __restrict__ deg0, const int* __restrict__ deg1,
                                                   const float* __restrict__ w0, const float* __restrict__ w1,
                                                   const float* __restrict__ bias,
                                                   float* __restrict__ mu0, float* __restrict__ mu1,
                                                   float* __restrict__ accum, int layer_off, int n) {
  constexpr int C = M / 2;
  constexpr int V = M / 64;   // fp8 bytes (channels) per lane: 4 or 2
  constexpr int U = 16;       // 16 independent row-gathers in flight (scalar metadata)

  int t = blockIdx.y;
  const unsigned char* Hf8 = t ? H1 : H0;
  const int* csr = t ? csr1 : csr0;
  const int* off = t ? off1 : off0;
  const int* deg = t ? deg1 : deg0;
  const float* w = t ? w1 : w0;
  float* mu = t ? mu1 : mu0;
  float* ixz_accum = accum + layer_off + 2 * t;

  __shared__ float red[4];
  int wid = threadIdx.x >> 6, lane = threadIdx.x & 63;
  int wave = blockIdx.x * 4 + wid;
  float ixz = 0.f;

  if (wave < n) {
    int d     = __builtin_amdgcn_readfirstlane(deg[wave]);
    int start = __builtin_amdgcn_readfirstlane(off[wave]);
    float norm = 1.0f / (float)d;
    int c0 = lane * V;

    float acc[V];
#pragma unroll
    for (int k = 0; k < V; k++) acc[k] = 0.f;

    for (int e0 = 0; e0 < d; e0 += U) {
      int idxs[U];
      float ws[U];
#pragma unroll
      for (int u = 0; u < U; u++) {
        int ee = e0 + u;
        int ap = start + (ee < d ? ee : 0);  // clamped, always-valid address
        idxs[u] = csr[ap];
        ws[u]   = (ee < d) ? w[ap] : 0.f;
      }
      unsigned int hv[U];
#pragma unroll
      for (int u = 0; u < U; u++) {
        if constexpr (V == 4)
          hv[u] = *(const unsigned int*)(Hf8 + (size_t)idxs[u] * M + c0);
        else
          hv[u] = (unsigned int)*(const unsigned short*)(Hf8 + (size_t)idxs[u] * M + c0);
      }
#pragma unroll
      for (int u = 0; u < U; u++) {
#pragma unroll
        for (int k = 0; k < V; k++)
          acc[k] += ws[u] * fp82f((unsigned char)(hv[u] >> (8 * k)));
      }
    }

    if (c0 < C) {
#pragma unroll
      for (int k = 0; k < V; k++) {
        float a = acc[k] * norm + bias[c0 + k];
        acc[k] = a;
        ixz += 0.5f * a * a - 0.5f;
      }
      if constexpr (V == 4)
        *(f32x4*)(mu + (size_t)wave * C + c0) = *(f32x4*)acc;
      else
        *(f32x2*)(mu + (size_t)wave * C + c0) = *(f32x2*)acc;
    } else {
#pragma unroll
      for (int k = 0; k < V; k++) {
        float a = acc[k] * norm + bias[c0 + k];
        float sp = (a > 20.f) ? a : log1pf(__expf(a));  // softplus
        sp += 1e-10f;
        ixz += -__logf(sp) + 0.5f * sp * sp;
      }
    }
  }
#pragma unroll
  for (int o = 32; o > 0; o >>= 1) ixz += __shfl_xor(ixz, o);
  if (lane == 0) red[wid] = ixz;
  __syncthreads();
  if (threadIdx.x == 0)
    atomicAdd(ixz_accum, red[0] + red[1] + red[2] + red[3]);
}

// ---------------- layer-1 temporal fusion + ReLU -> bf16 layer-2 inputs ----------------
__global__ void fuse1_kernel(const float* __restrict__ mu0, const float* __restrict__ mu1,
                             __hip_bfloat16* __restrict__ x0, __hip_bfloat16* __restrict__ x1, int n) {
  int i = blockIdx.x * blockDim.x + threadIdx.x;
  if (i < n) {
    float m0 = mu0[i], m1 = mu1[i];
    x0[i] = __float2bfloat16(fmaxf(m0, 0.f));
    x1[i] = __float2bfloat16(fmaxf(0.4f * m0 + 0.2f * m1, 0.f));
  }
}

// ---------------- layer-2 temporal fusion -> final output (fp32) + scalars ----------------
__global__ void fuse2_kernel(const float* __restrict__ mu0, const float* __restrict__ mu1,
                             float* __restrict__ out, const float* __restrict__ accum, int n) {
  int i = blockIdx.x * blockDim.x + threadIdx.x;
  if (i < n) {
    float m0 = mu0[i], m1 = mu1[i];
    out[i] = m0;
    out[n + i] = 0.4f * m0 + 0.2f * m1;
  }
  if (blockIdx.x == 0 && threadIdx.x == 0) {
    out[2 * n]     = (accum[0] + accum[2] + accum[4] + accum[6]) / (4.0f * (float)N_NODES);
    out[2 * n + 1] = (accum[1] + accum[3] + accum[5] + accum[7]) / (4.0f * (float)N_EDGES);
  }
}

extern "C" void kernel_launch(void* const* d_in, const int* in_sizes, int n_in,
                              void* d_out, int out_size, void* d_ws, size_t ws_size,
                              hipStream_t stream) {
  const float* x_all = (const float*)d_in[0];
  const int* ei      = (const int*)d_in[1];
  const float* W1    = (const float*)d_in[2];
  const float* att1  = (const float*)d_in[3];
  const float* b1    = (const float*)d_in[4];
  const float* W2    = (const float*)d_in[5];
  const float* att2  = (const float*)d_in[6];
  const float* b2    = (const float*)d_in[7];
  float* out         = (float*)d_out;

  char* ws = (char*)d_ws;
  size_t off = 0;
  auto alloc = [&](size_t bytes) {
    char* p = ws + off;
    off = (off + bytes + 255) & ~(size_t)255;
    return p;
  };
  unsigned short* wt1  = (unsigned short*)alloc(256 * 128 * sizeof(short));
  unsigned short* wt2  = (unsigned short*)alloc(128 * 128 * sizeof(short));
  unsigned char* hf8_0 = (unsigned char*)alloc((size_t)N_NODES * 256);
  unsigned char* hf8_1 = (unsigned char*)alloc((size_t)N_NODES * 256);
  float* si0   = (float*)alloc(N_NODES * sizeof(float));
  float* si1   = (float*)alloc(N_NODES * sizeof(float));
  float* sj0   = (float*)alloc(N_NODES * sizeof(float));
  float* sj1   = (float*)alloc(N_NODES * sizeof(float));
  float* mu1_0 = (float*)alloc((size_t)N_NODES * 128 * sizeof(float));
  float* mu1_1 = (float*)alloc((size_t)N_NODES * 128 * sizeof(float));
  __hip_bfloat16* x2_0 = (__hip_bfloat16*)alloc((size_t)N_NODES * 128 * sizeof(short));
  __hip_bfloat16* x2_1 = (__hip_bfloat16*)alloc((size_t)N_NODES * 128 * sizeof(short));
  // mu2 buffers alias mu1_0's region (mu1 dead after fuse1; stream-ordered)
  float* mu2_0 = mu1_0;
  float* mu2_1 = mu1_0 + (size_t)N_NODES * 64;
  int* degp[2]  = {(int*)alloc(N_NODES * 4), (int*)alloc(N_NODES * 4)};
  int* offp[2]  = {(int*)alloc(N_NODES * 4), (int*)alloc(N_NODES * 4)};
  int* curp[2]  = {(int*)alloc(N_NODES * 4), (int*)alloc(N_NODES * 4)};
  int* csrp[2]  = {(int*)alloc(N_EDGES * 4), (int*)alloc(N_EDGES * 4)};
  int* dstcp[2] = {(int*)alloc(N_EDGES * 4), (int*)alloc(N_EDGES * 4)};
  float* wc0    = (float*)alloc(N_EDGES * 4);
  float* wc1    = (float*)alloc(N_EDGES * 4);
  float* accum  = (float*)alloc(8 * sizeof(float));

  hipMemsetAsync(degp[0], 0, N_NODES * 4, stream);
  hipMemsetAsync(degp[1], 0, N_NODES * 4, stream);
  hipMemsetAsync(accum, 0, 8 * sizeof(float), stream);

  transpose_w_kernel<<<192, 256, 0, stream>>>(W1, wt1, W2, wt2);

  deg_kernel<<<(2 * N_EDGES + 255) / 256, 256, 0, stream>>>(ei, degp[0], degp[1], N_EDGES);
  scan_kernel<<<2, 1024, 0, stream>>>(degp[0], offp[0], curp[0], degp[1], offp[1], curp[1], N_NODES);
  scatter_kernel<<<(2 * N_EDGES + 255) / 256, 256, 0, stream>>>(ei, curp[0], curp[1],
                                                                csrp[0], csrp[1],
                                                                dstcp[0], dstcp[1], N_EDGES);

  dim3 ggrid(469, 2), egrid((N_EDGES + 255) / 256, 2), agrid(7500, 2);

  // ---- layer 1 (C = 128, M = 256) ----
  const float* x0 = x_all;
  const float* x1 = x_all + (size_t)N_NODES * K_DIM;
  gemm_kernel<256, true><<<ggrid, 256, 0, stream>>>(x0, x1, (const short*)wt1, hf8_0, hf8_1,
                                                    att1, si0, si1, sj0, sj1, N_NODES);
  edge_p_kernel<<<egrid, 256, 0, stream>>>(csrp[0], csrp[1], dstcp[0], dstcp[1],
                                           si0, si1, sj0, sj1, wc0, wc1, accum, 0, N_EDGES);
  aggr_kernel<256><<<agrid, 256, 0, stream>>>(hf8_0, hf8_1, csrp[0], csrp[1], offp[0], offp[1],
                                              degp[0], degp[1], wc0, wc1, b1,
                                              mu1_0, mu1_1, accum, 0, N_NODES);
  fuse1_kernel<<<(N_NODES * 128 + 255) / 256, 256, 0, stream>>>(mu1_0, mu1_1, x2_0, x2_1, N_NODES * 128);

  // ---- layer 2 (C = 64, M = 128) ----
  gemm_kernel<128, false><<<ggrid, 256, 0, stream>>>(x2_0, x2_1, (const short*)wt2, hf8_0, hf8_1,
                                                     att2, si0, si1, sj0, sj1, N_NODES);
  edge_p_kernel<<<egrid, 256, 0, stream>>>(csrp[0], csrp[1], dstcp[0], dstcp[1],
                                           si0, si1, sj0, sj1, wc0, wc1, accum, 4, N_EDGES);
  aggr_kernel<128><<<agrid, 256, 0, stream>>>(hf8_0, hf8_1, csrp[0], csrp[1], offp[0], offp[1],
                                              degp[0], degp[1], wc0, wc1, b2,
                                              mu2_0, mu2_1, accum, 4, N_NODES);
  fuse2_kernel<<<(N_NODES * 64 + 255) / 256, 256, 0, stream>>>(mu2_0, mu2_1, out, accum, N_NODES * 64);
}

// Round 11
// 644.999 us; speedup vs baseline: 1.3386x; 1.2990x over previous
//
#include <hip/hip_runtime.h>
#include <hip/hip_bf16.h>
#include <hip/hip_fp8.h>

#define N_NODES 30000
#define N_EDGES 510000
#define K_DIM   128
#define ABLK    7500   // aggr blocks per snapshot (4 nodes/block)

typedef short bf16x8 __attribute__((ext_vector_type(8)));
typedef float f32x4  __attribute__((ext_vector_type(4)));
typedef float f32x2  __attribute__((ext_vector_type(2)));

__device__ __forceinline__ unsigned short f2bf(float f) {
  __hip_bfloat16 h = __float2bfloat16(f);
  return *(unsigned short*)&h;
}
__device__ __forceinline__ unsigned char f2fp8(float f) {
  __hip_fp8_e4m3 q(f);
  return (unsigned char)q.__x;
}
__device__ __forceinline__ float fp82f(unsigned char u) {
  __hip_fp8_e4m3 q;
  q.__x = (__hip_fp8_storage_t)u;
  return (float)q;
}

// ---------------- both W transposes (K x M fp32) -> (M x K bf16) ----------------
__global__ void transpose_w_kernel(const float* __restrict__ W1, unsigned short* __restrict__ Wt1,
                                   const float* __restrict__ W2, unsigned short* __restrict__ Wt2) {
  int i = blockIdx.x * blockDim.x + threadIdx.x;
  if (i < 128 * 256) {
    int k = i >> 8, m = i & 255;
    Wt1[m * 128 + k] = f2bf(W1[i]);
  } else if (i < 128 * 256 + 128 * 128) {
    int j = i - 128 * 256;
    int k = j >> 7, m = j & 127;
    Wt2[m * 128 + k] = f2bf(W2[j]);
  }
}

// ---------------- degree for both snapshots ----------------
__global__ void deg_kernel(const int* __restrict__ ei, int* __restrict__ deg0,
                           int* __restrict__ deg1, int e) {
  int i = blockIdx.x * blockDim.x + threadIdx.x;
  if (i < 2 * e) {
    int t = i >= e ? 1 : 0;
    int j = i - t * e;
    int d = ei[(size_t)t * 2 * e + e + j];
    atomicAdd(&(t ? deg1 : deg0)[d], 1);
  }
}

// ---------------- exclusive scan (3-phase), one block per snapshot ----------------
__global__ __launch_bounds__(1024) void scan_kernel(const int* __restrict__ deg0, int* __restrict__ off0, int* __restrict__ cur0,
                                                    const int* __restrict__ deg1, int* __restrict__ off1, int* __restrict__ cur1,
                                                    int n) {
  const int* deg = blockIdx.x ? deg1 : deg0;
  int* off = blockIdx.x ? off1 : off0;
  int* cur = blockIdx.x ? cur1 : cur0;
  const int CHUNK = 30;  // 1024*30 >= 30000
  __shared__ int wsum[16];
  int tid = threadIdx.x;
  int base = tid * CHUNK;
  int sum = 0;
  for (int i = 0; i < CHUNK; i++)
    if (base + i < n) sum += deg[base + i];
  int lane = tid & 63, wid = tid >> 6;
  int incl = sum;
#pragma unroll
  for (int o = 1; o < 64; o <<= 1) {
    int v = __shfl_up(incl, o);
    if (lane >= o) incl += v;
  }
  if (lane == 63) wsum[wid] = incl;
  __syncthreads();
  if (tid == 0) {
    int run = 0;
    for (int w = 0; w < 16; w++) { int v = wsum[w]; wsum[w] = run; run += v; }
  }
  __syncthreads();
  int run = incl - sum + wsum[wid];
  for (int i = 0; i < CHUNK; i++) {
    if (base + i < n) {
      off[base + i] = run;
      cur[base + i] = run;
      run += deg[base + i];
    }
  }
}

// ---------------- scatter edges into CSR for both snapshots ----------------
__global__ void scatter_kernel(const int* __restrict__ ei,
                               int* __restrict__ cur0, int* __restrict__ cur1,
                               int* __restrict__ csr0, int* __restrict__ csr1, int e) {
  int i = blockIdx.x * blockDim.x + threadIdx.x;
  if (i < 2 * e) {
    int t = i >= e ? 1 : 0;
    int j = i - t * e;
    int s = ei[(size_t)t * 2 * e + j];
    int d = ei[(size_t)t * 2 * e + e + j];
    int* cur = t ? cur1 : cur0;
    int* csr = t ? csr1 : csr0;
    int p = atomicAdd(&cur[d], 1);
    csr[p] = s;
  }
}

// ---------------- fused GEMM + fp8-H write + per-node attention scores (both t) ----------------
template<int M, bool F32IN>
__global__ __launch_bounds__(256) void gemm_kernel(const void* __restrict__ X0v,
                                                   const void* __restrict__ X1v,
                                                   const short* __restrict__ Wt,
                                                   unsigned char* __restrict__ H0,
                                                   unsigned char* __restrict__ H1,
                                                   const float* __restrict__ att,
                                                   float* __restrict__ si0, float* __restrict__ si1,
                                                   float* __restrict__ sj0, float* __restrict__ sj1,
                                                   int nrows) {
  int t = blockIdx.y;
  const void* Xv = t ? X1v : X0v;
  unsigned char* Hf8 = t ? H1 : H0;
  float* s_i = t ? si1 : si0;
  float* s_j = t ? sj1 : sj0;

  int wave = blockIdx.x * 4 + (threadIdx.x >> 6);
  int lane = threadIdx.x & 63;
  if (wave * 16 >= nrows) return;
  int m16 = lane & 15, quad = lane >> 4;

  bf16x8 a[4];
  size_t arow = (size_t)(wave * 16 + m16) * K_DIM + quad * 8;
  if constexpr (F32IN) {
    const float* X = (const float*)Xv;
#pragma unroll
    for (int kc = 0; kc < 4; kc++) {
      f32x4 lo = *(const f32x4*)(X + arow + kc * 32);
      f32x4 hi = *(const f32x4*)(X + arow + kc * 32 + 4);
#pragma unroll
      for (int j = 0; j < 4; j++) {
        ((unsigned short*)&a[kc])[j]     = f2bf(lo[j]);
        ((unsigned short*)&a[kc])[4 + j] = f2bf(hi[j]);
      }
    }
  } else {
    const short* X = (const short*)Xv;
#pragma unroll
    for (int kc = 0; kc < 4; kc++) a[kc] = *(const bf16x8*)(X + arow + kc * 32);
  }

  float sip[4] = {0.f, 0.f, 0.f, 0.f}, sjp[4] = {0.f, 0.f, 0.f, 0.f};
#pragma unroll
  for (int nt = 0; nt < M / 16; nt++) {
    f32x4 acc = {0.f, 0.f, 0.f, 0.f};
    size_t brow = (size_t)(nt * 16 + m16) * K_DIM + quad * 8;
#pragma unroll
    for (int kc = 0; kc < 4; kc++) {
      bf16x8 b = *(const bf16x8*)(Wt + brow + kc * 32);
      acc = __builtin_amdgcn_mfma_f32_16x16x32_bf16(a[kc], b, acc, 0, 0, 0);
    }
    int col = nt * 16 + m16;
    float aA = att[col], aB = att[M + col];
#pragma unroll
    for (int r = 0; r < 4; r++) {
      int row = wave * 16 + quad * 4 + r;
      Hf8[(size_t)row * M + col] = f2fp8(acc[r]);
      sip[r] += acc[r] * aA;
      sjp[r] += acc[r] * aB;
    }
  }
#pragma unroll
  for (int o = 1; o < 16; o <<= 1) {
#pragma unroll
    for (int r = 0; r < 4; r++) {
      sip[r] += __shfl_xor(sip[r], o);
      sjp[r] += __shfl_xor(sjp[r], o);
    }
  }
  if (m16 == 0) {
#pragma unroll
    for (int r = 0; r < 4; r++) {
      int row = wave * 16 + quad * 4 + r;
      s_i[row] = sip[r];
      s_j[row] = sjp[r];
    }
  }
}

// ---------------- per-node gather with inline p + mu + ixz + skl (both t) ----------------
// csr indices are wave-uniform (SGPR) -> s_j[idx] is a scalar load; p is computed
// wave-uniform WHILE the H-row gathers (dependent only on idx) are in flight.
// NO global atomics: per-block partial {ixz,skl} stored to partials[bid].
template<int M>  // M = 2C
__global__ __launch_bounds__(256) void aggr_kernel(const unsigned char* __restrict__ H0,
                                                   const unsigned char* __restrict__ H1,
                                                   const int* __restrict__ csr0, const int* __restrict__ csr1,
                                                   const int* __restrict__ off0, const int* __restrict__ off1,
                                                   const int* __restrict__ deg0, const int* __restrict__ deg1,
                                                   const float* __restrict__ si0, const float* __restrict__ si1,
                                                   const float* __restrict__ sj0, const float* __restrict__ sj1,
                                                   const float* __restrict__ bias,
                                                   float* __restrict__ mu0, float* __restrict__ mu1,
                                                   f32x2* __restrict__ partials,  // [2*ABLK]
                                                   int n) {
  constexpr int C = M / 2;
  constexpr int V = M / 64;   // fp8 bytes (channels) per lane: 4 or 2
  constexpr int U = 16;       // 16 independent row-gathers in flight (scalar metadata)

  int t = blockIdx.y;
  const unsigned char* Hf8 = t ? H1 : H0;
  const int* csr = t ? csr1 : csr0;
  const int* off = t ? off1 : off0;
  const int* deg = t ? deg1 : deg0;
  const float* s_i = t ? si1 : si0;
  const float* s_j = t ? sj1 : sj0;
  float* mu = t ? mu1 : mu0;

  __shared__ float red_i[4], red_s[4];
  int wid = threadIdx.x >> 6, lane = threadIdx.x & 63;
  int wave = blockIdx.x * 4 + wid;
  float ixz = 0.f, skl = 0.f;

  if (wave < n) {
    int d     = __builtin_amdgcn_readfirstlane(deg[wave]);
    int start = __builtin_amdgcn_readfirstlane(off[wave]);
    float si  = s_i[wave];
    float norm = 1.0f / (float)d;
    int c0 = lane * V;
    const float q   = 1.0f / (1.0f + __expf(-(1.0f / 15.0f)));
    const float lq  = __logf(q);
    const float l1q = __logf(1.0f - q);

    float acc[V];
#pragma unroll
    for (int k = 0; k < V; k++) acc[k] = 0.f;

    for (int e0 = 0; e0 < d; e0 += U) {
      int idxs[U];
#pragma unroll
      for (int u = 0; u < U; u++) {
        int ee = e0 + u;
        int ap = start + (ee < d ? ee : 0);  // clamped, always-valid address
        idxs[u] = __builtin_amdgcn_readfirstlane(csr[ap]);
      }
      // H-row gathers: depend only on idxs -> issue immediately
      unsigned int hv[U];
#pragma unroll
      for (int u = 0; u < U; u++) {
        if constexpr (V == 4)
          hv[u] = *(const unsigned int*)(Hf8 + (size_t)idxs[u] * M + c0);
        else
          hv[u] = (unsigned int)*(const unsigned short*)(Hf8 + (size_t)idxs[u] * M + c0);
      }
      // p computed (wave-uniform) while gathers are in flight
      float ws[U];
#pragma unroll
      for (int u = 0; u < U; u++) {
        bool valid = (e0 + u) < d;
        float lg = si + s_j[idxs[u]];
        lg = lg > 0.f ? lg : 0.2f * lg;          // leaky_relu
        float p = 1.0f / (1.0f + __expf(-lg));   // sigmoid
        p = fminf(fmaxf(p, 0.01f), 0.99f);       // clip
        if (valid)
          skl += p * (__logf(p) - lq) + (1.0f - p) * (__logf(1.0f - p) - l1q);
        ws[u] = valid ? p : 0.f;
      }
#pragma unroll
      for (int u = 0; u < U; u++) {
#pragma unroll
        for (int k = 0; k < V; k++)
          acc[k] += ws[u] * fp82f((unsigned char)(hv[u] >> (8 * k)));
      }
    }

    if (c0 < C) {
#pragma unroll
      for (int k = 0; k < V; k++) {
        float a = acc[k] * norm + bias[c0 + k];
        acc[k] = a;
        ixz += 0.5f * a * a - 0.5f;
      }
      if constexpr (V == 4)
        *(f32x4*)(mu + (size_t)wave * C + c0) = *(f32x4*)acc;
      else
        *(f32x2*)(mu + (size_t)wave * C + c0) = *(f32x2*)acc;
    } else {
#pragma unroll
      for (int k = 0; k < V; k++) {
        float a = acc[k] * norm + bias[c0 + k];
        float sp = (a > 20.f) ? a : log1pf(__expf(a));  // softplus
        sp += 1e-10f;
        ixz += -__logf(sp) + 0.5f * sp * sp;
      }
    }
  }
  // skl is lane-uniform; ixz needs the cross-lane reduce
#pragma unroll
  for (int o = 32; o > 0; o >>= 1) ixz += __shfl_xor(ixz, o);
  if (lane == 0) { red_i[wid] = ixz; red_s[wid] = skl; }
  __syncthreads();
  if (threadIdx.x == 0) {
    f32x2 pr;
    pr[0] = red_i[0] + red_i[1] + red_i[2] + red_i[3];
    pr[1] = red_s[0] + red_s[1] + red_s[2] + red_s[3];
    partials[t * ABLK + blockIdx.x] = pr;  // plain store, no atomic
  }
}

// ---------------- layer-1 temporal fusion + ReLU -> bf16 layer-2 inputs ----------------
__global__ void fuse1_kernel(const float* __restrict__ mu0, const float* __restrict__ mu1,
                             __hip_bfloat16* __restrict__ x0, __hip_bfloat16* __restrict__ x1, int n) {
  int i = blockIdx.x * blockDim.x + threadIdx.x;
  if (i < n) {
    float m0 = mu0[i], m1 = mu1[i];
    x0[i] = __float2bfloat16(fmaxf(m0, 0.f));
    x1[i] = __float2bfloat16(fmaxf(0.4f * m0 + 0.2f * m1, 0.f));
  }
}

// ---------------- layer-2 temporal fusion -> final output (fp32) ----------------
__global__ void fuse2_kernel(const float* __restrict__ mu0, const float* __restrict__ mu1,
                             float* __restrict__ out, int n) {
  int i = blockIdx.x * blockDim.x + threadIdx.x;
  if (i < n) {
    float m0 = mu0[i], m1 = mu1[i];
    out[i] = m0;
    out[n + i] = 0.4f * m0 + 0.2f * m1;
  }
}

// ---------------- final reduction of per-block partials -> scalars ----------------
__global__ __launch_bounds__(1024) void reduce_kernel(const f32x2* __restrict__ p1,
                                                      const f32x2* __restrict__ p2,
                                                      float* __restrict__ out2) {
  __shared__ float ri[16], rs[16];
  float ixz = 0.f, skl = 0.f;
  for (int i = threadIdx.x; i < 2 * ABLK; i += 1024) {
    f32x2 a = p1[i], b = p2[i];
    ixz += a[0] + b[0];
    skl += a[1] + b[1];
  }
  int lane = threadIdx.x & 63, wid = threadIdx.x >> 6;
#pragma unroll
  for (int o = 32; o > 0; o >>= 1) {
    ixz += __shfl_xor(ixz, o);
    skl += __shfl_xor(skl, o);
  }
  if (lane == 0) { ri[wid] = ixz; rs[wid] = skl; }
  __syncthreads();
  if (threadIdx.x == 0) {
    float si = 0.f, ss = 0.f;
    for (int w = 0; w < 16; w++) { si += ri[w]; ss += rs[w]; }
    out2[0] = si / (4.0f * (float)N_NODES);
    out2[1] = ss / (4.0f * (float)N_EDGES);
  }
}

extern "C" void kernel_launch(void* const* d_in, const int* in_sizes, int n_in,
                              void* d_out, int out_size, void* d_ws, size_t ws_size,
                              hipStream_t stream) {
  const float* x_all = (const float*)d_in[0];
  const int* ei      = (const int*)d_in[1];
  const float* W1    = (const float*)d_in[2];
  const float* att1  = (const float*)d_in[3];
  const float* b1    = (const float*)d_in[4];
  const float* W2    = (const float*)d_in[5];
  const float* att2  = (const float*)d_in[6];
  const float* b2    = (const float*)d_in[7];
  float* out         = (float*)d_out;

  char* ws = (char*)d_ws;
  size_t off = 0;
  auto alloc = [&](size_t bytes) {
    char* p = ws + off;
    off = (off + bytes + 255) & ~(size_t)255;
    return p;
  };
  unsigned short* wt1  = (unsigned short*)alloc(256 * 128 * sizeof(short));
  unsigned short* wt2  = (unsigned short*)alloc(128 * 128 * sizeof(short));
  unsigned char* hf8_0 = (unsigned char*)alloc((size_t)N_NODES * 256);
  unsigned char* hf8_1 = (unsigned char*)alloc((size_t)N_NODES * 256);
  float* si0   = (float*)alloc(N_NODES * sizeof(float));
  float* si1   = (float*)alloc(N_NODES * sizeof(float));
  float* sj0   = (float*)alloc(N_NODES * sizeof(float));
  float* sj1   = (float*)alloc(N_NODES * sizeof(float));
  float* mu1_0 = (float*)alloc((size_t)N_NODES * 128 * sizeof(float));
  float* mu1_1 = (float*)alloc((size_t)N_NODES * 128 * sizeof(float));
  __hip_bfloat16* x2_0 = (__hip_bfloat16*)alloc((size_t)N_NODES * 128 * sizeof(short));
  __hip_bfloat16* x2_1 = (__hip_bfloat16*)alloc((size_t)N_NODES * 128 * sizeof(short));
  // mu2 buffers alias mu1_0's region (mu1 dead after fuse1; stream-ordered)
  float* mu2_0 = mu1_0;
  float* mu2_1 = mu1_0 + (size_t)N_NODES * 64;
  int* degp[2]  = {(int*)alloc(N_NODES * 4), (int*)alloc(N_NODES * 4)};
  int* offp[2]  = {(int*)alloc(N_NODES * 4), (int*)alloc(N_NODES * 4)};
  int* curp[2]  = {(int*)alloc(N_NODES * 4), (int*)alloc(N_NODES * 4)};
  int* csrp[2]  = {(int*)alloc(N_EDGES * 4), (int*)alloc(N_EDGES * 4)};
  f32x2* part1  = (f32x2*)alloc(2 * ABLK * sizeof(f32x2));
  f32x2* part2  = (f32x2*)alloc(2 * ABLK * sizeof(f32x2));

  hipMemsetAsync(degp[0], 0, N_NODES * 4, stream);
  hipMemsetAsync(degp[1], 0, N_NODES * 4, stream);

  transpose_w_kernel<<<192, 256, 0, stream>>>(W1, wt1, W2, wt2);

  deg_kernel<<<(2 * N_EDGES + 255) / 256, 256, 0, stream>>>(ei, degp[0], degp[1], N_EDGES);
  scan_kernel<<<2, 1024, 0, stream>>>(degp[0], offp[0], curp[0], degp[1], offp[1], curp[1], N_NODES);
  scatter_kernel<<<(2 * N_EDGES + 255) / 256, 256, 0, stream>>>(ei, curp[0], curp[1],
                                                                csrp[0], csrp[1], N_EDGES);

  dim3 ggrid(469, 2), agrid(ABLK, 2);

  // ---- layer 1 (C = 128, M = 256) ----
  const float* x0 = x_all;
  const float* x1 = x_all + (size_t)N_NODES * K_DIM;
  gemm_kernel<256, true><<<ggrid, 256, 0, stream>>>(x0, x1, (const short*)wt1, hf8_0, hf8_1,
                                                    att1, si0, si1, sj0, sj1, N_NODES);
  aggr_kernel<256><<<agrid, 256, 0, stream>>>(hf8_0, hf8_1, csrp[0], csrp[1], offp[0], offp[1],
                                              degp[0], degp[1], si0, si1, sj0, sj1, b1,
                                              mu1_0, mu1_1, part1, N_NODES);
  fuse1_kernel<<<(N_NODES * 128 + 255) / 256, 256, 0, stream>>>(mu1_0, mu1_1, x2_0, x2_1, N_NODES * 128);

  // ---- layer 2 (C = 64, M = 128) ----
  gemm_kernel<128, false><<<ggrid, 256, 0, stream>>>(x2_0, x2_1, (const short*)wt2, hf8_0, hf8_1,
                                                     att2, si0, si1, sj0, sj1, N_NODES);
  aggr_kernel<128><<<agrid, 256, 0, stream>>>(hf8_0, hf8_1, csrp[0], csrp[1], offp[0], offp[1],
                                              degp[0], degp[1], si0, si1, sj0, sj1, b2,
                                              mu2_0, mu2_1, part2, N_NODES);
  fuse2_kernel<<<(N_NODES * 64 + 255) / 256, 256, 0, stream>>>(mu2_0, mu2_1, out, N_NODES * 64);
  reduce_kernel<<<1, 1024, 0, stream>>>(part1, part2, out + (size_t)2 * N_NODES * 64);
}

// Round 12
// 591.946 us; speedup vs baseline: 1.4586x; 1.0896x over previous
//
#include <hip/hip_runtime.h>
#include <hip/hip_bf16.h>
#include <hip/hip_fp8.h>

#define N_NODES 30000
#define N_EDGES 510000
#define K_DIM   128
#define ABLK    7500   // aggr blocks per snapshot (4 nodes/block)

typedef short bf16x8 __attribute__((ext_vector_type(8)));
typedef float f32x4  __attribute__((ext_vector_type(4)));
typedef float f32x2  __attribute__((ext_vector_type(2)));
typedef unsigned int u32x2 __attribute__((ext_vector_type(2)));

__device__ __forceinline__ unsigned short f2bf(float f) {
  __hip_bfloat16 h = __float2bfloat16(f);
  return *(unsigned short*)&h;
}
__device__ __forceinline__ unsigned char f2fp8(float f) {
  __hip_fp8_e4m3 q(f);
  return (unsigned char)q.__x;
}

// ---------------- both W transposes (K x M fp32) -> (M x K bf16) ----------------
__global__ void transpose_w_kernel(const float* __restrict__ W1, unsigned short* __restrict__ Wt1,
                                   const float* __restrict__ W2, unsigned short* __restrict__ Wt2) {
  int i = blockIdx.x * blockDim.x + threadIdx.x;
  if (i < 128 * 256) {
    int k = i >> 8, m = i & 255;
    Wt1[m * 128 + k] = f2bf(W1[i]);
  } else if (i < 128 * 256 + 128 * 128) {
    int j = i - 128 * 256;
    int k = j >> 7, m = j & 127;
    Wt2[m * 128 + k] = f2bf(W2[j]);
  }
}

// ---------------- degree for both snapshots ----------------
__global__ void deg_kernel(const int* __restrict__ ei, int* __restrict__ deg0,
                           int* __restrict__ deg1, int e) {
  int i = blockIdx.x * blockDim.x + threadIdx.x;
  if (i < 2 * e) {
    int t = i >= e ? 1 : 0;
    int j = i - t * e;
    int d = ei[(size_t)t * 2 * e + e + j];
    atomicAdd(&(t ? deg1 : deg0)[d], 1);
  }
}

// ---------------- exclusive scan (3-phase), one block per snapshot ----------------
__global__ __launch_bounds__(1024) void scan_kernel(const int* __restrict__ deg0, int* __restrict__ off0, int* __restrict__ cur0,
                                                    const int* __restrict__ deg1, int* __restrict__ off1, int* __restrict__ cur1,
                                                    int n) {
  const int* deg = blockIdx.x ? deg1 : deg0;
  int* off = blockIdx.x ? off1 : off0;
  int* cur = blockIdx.x ? cur1 : cur0;
  const int CHUNK = 30;  // 1024*30 >= 30000
  __shared__ int wsum[16];
  int tid = threadIdx.x;
  int base = tid * CHUNK;
  int sum = 0;
  for (int i = 0; i < CHUNK; i++)
    if (base + i < n) sum += deg[base + i];
  int lane = tid & 63, wid = tid >> 6;
  int incl = sum;
#pragma unroll
  for (int o = 1; o < 64; o <<= 1) {
    int v = __shfl_up(incl, o);
    if (lane >= o) incl += v;
  }
  if (lane == 63) wsum[wid] = incl;
  __syncthreads();
  if (tid == 0) {
    int run = 0;
    for (int w = 0; w < 16; w++) { int v = wsum[w]; wsum[w] = run; run += v; }
  }
  __syncthreads();
  int run = incl - sum + wsum[wid];
  for (int i = 0; i < CHUNK; i++) {
    if (base + i < n) {
      off[base + i] = run;
      cur[base + i] = run;
      run += deg[base + i];
    }
  }
}

// ---------------- scatter edges into CSR for both snapshots ----------------
__global__ void scatter_kernel(const int* __restrict__ ei,
                               int* __restrict__ cur0, int* __restrict__ cur1,
                               int* __restrict__ csr0, int* __restrict__ csr1, int e) {
  int i = blockIdx.x * blockDim.x + threadIdx.x;
  if (i < 2 * e) {
    int t = i >= e ? 1 : 0;
    int j = i - t * e;
    int s = ei[(size_t)t * 2 * e + j];
    int d = ei[(size_t)t * 2 * e + e + j];
    int* cur = t ? cur1 : cur0;
    int* csr = t ? csr1 : csr0;
    int p = atomicAdd(&cur[d], 1);
    csr[p] = s;
  }
}

// ---------------- fused GEMM + fp8-H write + per-node attention scores (both t) ----------------
template<int M, bool F32IN>
__global__ __launch_bounds__(256) void gemm_kernel(const void* __restrict__ X0v,
                                                   const void* __restrict__ X1v,
                                                   const short* __restrict__ Wt,
                                                   unsigned char* __restrict__ H0,
                                                   unsigned char* __restrict__ H1,
                                                   const float* __restrict__ att,
                                                   float* __restrict__ si0, float* __restrict__ si1,
                                                   float* __restrict__ sj0, float* __restrict__ sj1,
                                                   int nrows) {
  int t = blockIdx.y;
  const void* Xv = t ? X1v : X0v;
  unsigned char* Hf8 = t ? H1 : H0;
  float* s_i = t ? si1 : si0;
  float* s_j = t ? sj1 : sj0;

  int wave = blockIdx.x * 4 + (threadIdx.x >> 6);
  int lane = threadIdx.x & 63;
  if (wave * 16 >= nrows) return;
  int m16 = lane & 15, quad = lane >> 4;

  bf16x8 a[4];
  size_t arow = (size_t)(wave * 16 + m16) * K_DIM + quad * 8;
  if constexpr (F32IN) {
    const float* X = (const float*)Xv;
#pragma unroll
    for (int kc = 0; kc < 4; kc++) {
      f32x4 lo = *(const f32x4*)(X + arow + kc * 32);
      f32x4 hi = *(const f32x4*)(X + arow + kc * 32 + 4);
#pragma unroll
      for (int j = 0; j < 4; j++) {
        ((unsigned short*)&a[kc])[j]     = f2bf(lo[j]);
        ((unsigned short*)&a[kc])[4 + j] = f2bf(hi[j]);
      }
    }
  } else {
    const short* X = (const short*)Xv;
#pragma unroll
    for (int kc = 0; kc < 4; kc++) a[kc] = *(const bf16x8*)(X + arow + kc * 32);
  }

  float sip[4] = {0.f, 0.f, 0.f, 0.f}, sjp[4] = {0.f, 0.f, 0.f, 0.f};
#pragma unroll
  for (int nt = 0; nt < M / 16; nt++) {
    f32x4 acc = {0.f, 0.f, 0.f, 0.f};
    size_t brow = (size_t)(nt * 16 + m16) * K_DIM + quad * 8;
#pragma unroll
    for (int kc = 0; kc < 4; kc++) {
      bf16x8 b = *(const bf16x8*)(Wt + brow + kc * 32);
      acc = __builtin_amdgcn_mfma_f32_16x16x32_bf16(a[kc], b, acc, 0, 0, 0);
    }
    int col = nt * 16 + m16;
    float aA = att[col], aB = att[M + col];
#pragma unroll
    for (int r = 0; r < 4; r++) {
      int row = wave * 16 + quad * 4 + r;
      Hf8[(size_t)row * M + col] = f2fp8(acc[r]);
      sip[r] += acc[r] * aA;
      sjp[r] += acc[r] * aB;
    }
  }
#pragma unroll
  for (int o = 1; o < 16; o <<= 1) {
#pragma unroll
    for (int r = 0; r < 4; r++) {
      sip[r] += __shfl_xor(sip[r], o);
      sjp[r] += __shfl_xor(sjp[r], o);
    }
  }
  if (m16 == 0) {
#pragma unroll
    for (int r = 0; r < 4; r++) {
      int row = wave * 16 + quad * 4 + r;
      s_i[row] = sip[r];
      s_j[row] = sjp[r];
    }
  }
}

// ---------------- per-node gather: packed rows/VMEM, lane-parallel p, pk-fp8 decode ----------------
// M=256: 2 edges per 8B-lane load (32 lanes/row); M=128: 4 edges/load (16 lanes/row).
// No global atomics: per-block partial {ixz,skl} stored to partials[bid].
template<int M>  // M = 2C
__global__ __launch_bounds__(256) void aggr_kernel(const unsigned char* __restrict__ H0,
                                                   const unsigned char* __restrict__ H1,
                                                   const int* __restrict__ csr0, const int* __restrict__ csr1,
                                                   const int* __restrict__ off0, const int* __restrict__ off1,
                                                   const int* __restrict__ deg0, const int* __restrict__ deg1,
                                                   const float* __restrict__ si0, const float* __restrict__ si1,
                                                   const float* __restrict__ sj0, const float* __restrict__ sj1,
                                                   const float* __restrict__ bias,
                                                   float* __restrict__ mu0, float* __restrict__ mu1,
                                                   f32x2* __restrict__ partials,  // [2*ABLK]
                                                   int n) {
  constexpr int C = M / 2;
  constexpr int LPR = M / 8;                  // lanes per row: 32 / 16
  constexpr int LOG2LPR = (M == 256) ? 5 : 4;
  constexpr int EPL = 64 / LPR;               // edges per load: 2 / 4
  constexpr int NL = 4;                       // loads per chunk
  constexpr int U = NL * EPL;                 // edges per chunk: 8 / 16

  int t = blockIdx.y;
  const unsigned char* Hf8 = t ? H1 : H0;
  const int* csr = t ? csr1 : csr0;
  const int* off = t ? off1 : off0;
  const int* deg = t ? deg1 : deg0;
  const float* s_i = t ? si1 : si0;
  const float* s_j = t ? sj1 : sj0;
  float* mu = t ? mu1 : mu0;

  __shared__ float red_i[4], red_s[4];
  int wid = threadIdx.x >> 6, lane = threadIdx.x & 63;
  int wave = blockIdx.x * 4 + wid;
  float ixz = 0.f, skl = 0.f;

  if (wave < n) {
    int d     = __builtin_amdgcn_readfirstlane(deg[wave]);
    int start = __builtin_amdgcn_readfirstlane(off[wave]);
    float si  = s_i[wave];
    float norm = 1.0f / (float)d;
    int sub = lane & (LPR - 1);
    int g   = lane >> LOG2LPR;
    int c0  = sub * 8;                 // 8 fp8 channels per lane
    const float q   = 1.0f / (1.0f + __expf(-(1.0f / 15.0f)));
    const float lq  = __logf(q);
    const float l1q = __logf(1.0f - q);

    float acc[8];
#pragma unroll
    for (int k = 0; k < 8; k++) acc[k] = 0.f;

    for (int e0 = 0; e0 < d; e0 += U) {
      // ---- lane-parallel edge metadata: lanes 0..U-1 own one edge each ----
      int ee = e0 + lane;
      bool val = (lane < U) && (ee < d);
      int ap = start + (val ? ee : (d - 1));   // clamped, always-valid
      int idxl = csr[ap];                      // 1 coalesced VMEM
      float sjl = s_j[idxl];                   // 1 small gather
      float lg = si + sjl;
      lg = lg > 0.f ? lg : 0.2f * lg;          // leaky_relu
      float p = 1.0f / (1.0f + __expf(-lg));   // sigmoid (one chain for U edges)
      p = fminf(fmaxf(p, 0.01f), 0.99f);       // clip
      float wl = val ? p : 0.f;
      if (val)
        skl += p * (__logf(p) - lq) + (1.0f - p) * (__logf(1.0f - p) - l1q);

      // ---- packed row gathers: NL loads, EPL edges each ----
      u32x2 hv[NL];
      float wsel[NL];
#pragma unroll
      for (int l = 0; l < NL; l++) {
        int idx; float wv_;
        if constexpr (EPL == 2) {
          int i0 = __shfl(idxl, l * 2), i1 = __shfl(idxl, l * 2 + 1);
          float w0 = __shfl(wl, l * 2), w1 = __shfl(wl, l * 2 + 1);
          idx = g ? i1 : i0;
          wv_ = g ? w1 : w0;
        } else {
          int i0 = __shfl(idxl, l * 4),     i1 = __shfl(idxl, l * 4 + 1);
          int i2 = __shfl(idxl, l * 4 + 2), i3 = __shfl(idxl, l * 4 + 3);
          float w0 = __shfl(wl, l * 4),     w1 = __shfl(wl, l * 4 + 1);
          float w2 = __shfl(wl, l * 4 + 2), w3 = __shfl(wl, l * 4 + 3);
          int ia = (g & 1) ? i1 : i0, ib = (g & 1) ? i3 : i2;
          idx = (g & 2) ? ib : ia;
          float fa = (g & 1) ? w1 : w0, fb = (g & 1) ? w3 : w2;
          wv_ = (g & 2) ? fb : fa;
        }
        wsel[l] = wv_;
        hv[l] = *(const u32x2*)(Hf8 + (size_t)idx * M + c0);
      }
      // ---- packed fp8 -> f32 decode + FMA ----
#pragma unroll
      for (int l = 0; l < NL; l++) {
        f32x2 d0 = __builtin_amdgcn_cvt_pk_f32_fp8((int)hv[l][0], false);
        f32x2 d1 = __builtin_amdgcn_cvt_pk_f32_fp8((int)hv[l][0], true);
        f32x2 d2 = __builtin_amdgcn_cvt_pk_f32_fp8((int)hv[l][1], false);
        f32x2 d3 = __builtin_amdgcn_cvt_pk_f32_fp8((int)hv[l][1], true);
        float wv_ = wsel[l];
        acc[0] += wv_ * d0[0]; acc[1] += wv_ * d0[1];
        acc[2] += wv_ * d1[0]; acc[3] += wv_ * d1[1];
        acc[4] += wv_ * d2[0]; acc[5] += wv_ * d2[1];
        acc[6] += wv_ * d3[0]; acc[7] += wv_ * d3[1];
      }
    }

    // combine lane-groups (same channels, different edges)
#pragma unroll
    for (int o = LPR; o < 64; o <<= 1) {
#pragma unroll
      for (int k = 0; k < 8; k++) acc[k] += __shfl_xor(acc[k], o);
    }

    if (lane < LPR) {
      if (c0 < C) {
        f32x4 m0, m1;
#pragma unroll
        for (int k = 0; k < 4; k++) {
          float a = acc[k] * norm + bias[c0 + k];
          m0[k] = a;
          ixz += 0.5f * a * a - 0.5f;
        }
#pragma unroll
        for (int k = 0; k < 4; k++) {
          float a = acc[4 + k] * norm + bias[c0 + 4 + k];
          m1[k] = a;
          ixz += 0.5f * a * a - 0.5f;
        }
        *(f32x4*)(mu + (size_t)wave * C + c0) = m0;
        *(f32x4*)(mu + (size_t)wave * C + c0 + 4) = m1;
      } else {
#pragma unroll
        for (int k = 0; k < 8; k++) {
          float a = acc[k] * norm + bias[c0 + k];
          float sp = (a > 20.f) ? a : log1pf(__expf(a));  // softplus
          sp += 1e-10f;
          ixz += -__logf(sp) + 0.5f * sp * sp;
        }
      }
    }
  }
#pragma unroll
  for (int o = 32; o > 0; o >>= 1) {
    ixz += __shfl_xor(ixz, o);
    skl += __shfl_xor(skl, o);
  }
  if (lane == 0) { red_i[wid] = ixz; red_s[wid] = skl; }
  __syncthreads();
  if (threadIdx.x == 0) {
    f32x2 pr;
    pr[0] = red_i[0] + red_i[1] + red_i[2] + red_i[3];
    pr[1] = red_s[0] + red_s[1] + red_s[2] + red_s[3];
    partials[t * ABLK + blockIdx.x] = pr;  // plain store, no atomic
  }
}

// ---------------- layer-1 temporal fusion + ReLU -> bf16 layer-2 inputs ----------------
__global__ void fuse1_kernel(const float* __restrict__ mu0, const float* __restrict__ mu1,
                             __hip_bfloat16* __restrict__ x0, __hip_bfloat16* __restrict__ x1, int n) {
  int i = blockIdx.x * blockDim.x + threadIdx.x;
  if (i < n) {
    float m0 = mu0[i], m1 = mu1[i];
    x0[i] = __float2bfloat16(fmaxf(m0, 0.f));
    x1[i] = __float2bfloat16(fmaxf(0.4f * m0 + 0.2f * m1, 0.f));
  }
}

// ---------------- layer-2 temporal fusion -> final output (fp32) ----------------
__global__ void fuse2_kernel(const float* __restrict__ mu0, const float* __restrict__ mu1,
                             float* __restrict__ out, int n) {
  int i = blockIdx.x * blockDim.x + threadIdx.x;
  if (i < n) {
    float m0 = mu0[i], m1 = mu1[i];
    out[i] = m0;
    out[n + i] = 0.4f * m0 + 0.2f * m1;
  }
}

// ---------------- final reduction of per-block partials -> scalars ----------------
__global__ __launch_bounds__(1024) void reduce_kernel(const f32x2* __restrict__ p1,
                                                      const f32x2* __restrict__ p2,
                                                      float* __restrict__ out2) {
  __shared__ float ri[16], rs[16];
  float ixz = 0.f, skl = 0.f;
  for (int i = threadIdx.x; i < 2 * ABLK; i += 1024) {
    f32x2 a = p1[i], b = p2[i];
    ixz += a[0] + b[0];
    skl += a[1] + b[1];
  }
  int lane = threadIdx.x & 63, wid = threadIdx.x >> 6;
#pragma unroll
  for (int o = 32; o > 0; o >>= 1) {
    ixz += __shfl_xor(ixz, o);
    skl += __shfl_xor(skl, o);
  }
  if (lane == 0) { ri[wid] = ixz; rs[wid] = skl; }
  __syncthreads();
  if (threadIdx.x == 0) {
    float si = 0.f, ss = 0.f;
    for (int w = 0; w < 16; w++) { si += ri[w]; ss += rs[w]; }
    out2[0] = si / (4.0f * (float)N_NODES);
    out2[1] = ss / (4.0f * (float)N_EDGES);
  }
}

extern "C" void kernel_launch(void* const* d_in, const int* in_sizes, int n_in,
                              void* d_out, int out_size, void* d_ws, size_t ws_size,
                              hipStream_t stream) {
  const float* x_all = (const float*)d_in[0];
  const int* ei      = (const int*)d_in[1];
  const float* W1    = (const float*)d_in[2];
  const float* att1  = (const float*)d_in[3];
  const float* b1    = (const float*)d_in[4];
  const float* W2    = (const float*)d_in[5];
  const float* att2  = (const float*)d_in[6];
  const float* b2    = (const float*)d_in[7];
  float* out         = (float*)d_out;

  char* ws = (char*)d_ws;
  size_t off = 0;
  auto alloc = [&](size_t bytes) {
    char* p = ws + off;
    off = (off + bytes + 255) & ~(size_t)255;
    return p;
  };
  unsigned short* wt1  = (unsigned short*)alloc(256 * 128 * sizeof(short));
  unsigned short* wt2  = (unsigned short*)alloc(128 * 128 * sizeof(short));
  unsigned char* hf8_0 = (unsigned char*)alloc((size_t)N_NODES * 256);
  unsigned char* hf8_1 = (unsigned char*)alloc((size_t)N_NODES * 256);
  float* si0   = (float*)alloc(N_NODES * sizeof(float));
  float* si1   = (float*)alloc(N_NODES * sizeof(float));
  float* sj0   = (float*)alloc(N_NODES * sizeof(float));
  float* sj1   = (float*)alloc(N_NODES * sizeof(float));
  float* mu1_0 = (float*)alloc((size_t)N_NODES * 128 * sizeof(float));
  float* mu1_1 = (float*)alloc((size_t)N_NODES * 128 * sizeof(float));
  __hip_bfloat16* x2_0 = (__hip_bfloat16*)alloc((size_t)N_NODES * 128 * sizeof(short));
  __hip_bfloat16* x2_1 = (__hip_bfloat16*)alloc((size_t)N_NODES * 128 * sizeof(short));
  // mu2 buffers alias mu1_0's region (mu1 dead after fuse1; stream-ordered)
  float* mu2_0 = mu1_0;
  float* mu2_1 = mu1_0 + (size_t)N_NODES * 64;
  int* degp[2]  = {(int*)alloc(N_NODES * 4), (int*)alloc(N_NODES * 4)};
  int* offp[2]  = {(int*)alloc(N_NODES * 4), (int*)alloc(N_NODES * 4)};
  int* curp[2]  = {(int*)alloc(N_NODES * 4), (int*)alloc(N_NODES * 4)};
  int* csrp[2]  = {(int*)alloc(N_EDGES * 4), (int*)alloc(N_EDGES * 4)};
  f32x2* part1  = (f32x2*)alloc(2 * ABLK * sizeof(f32x2));
  f32x2* part2  = (f32x2*)alloc(2 * ABLK * sizeof(f32x2));

  hipMemsetAsync(degp[0], 0, N_NODES * 4, stream);
  hipMemsetAsync(degp[1], 0, N_NODES * 4, stream);

  transpose_w_kernel<<<192, 256, 0, stream>>>(W1, wt1, W2, wt2);

  deg_kernel<<<(2 * N_EDGES + 255) / 256, 256, 0, stream>>>(ei, degp[0], degp[1], N_EDGES);
  scan_kernel<<<2, 1024, 0, stream>>>(degp[0], offp[0], curp[0], degp[1], offp[1], curp[1], N_NODES);
  scatter_kernel<<<(2 * N_EDGES + 255) / 256, 256, 0, stream>>>(ei, curp[0], curp[1],
                                                                csrp[0], csrp[1], N_EDGES);

  dim3 ggrid(469, 2), agrid(ABLK, 2);

  // ---- layer 1 (C = 128, M = 256) ----
  const float* x0 = x_all;
  const float* x1 = x_all + (size_t)N_NODES * K_DIM;
  gemm_kernel<256, true><<<ggrid, 256, 0, stream>>>(x0, x1, (const short*)wt1, hf8_0, hf8_1,
                                                    att1, si0, si1, sj0, sj1, N_NODES);
  aggr_kernel<256><<<agrid, 256, 0, stream>>>(hf8_0, hf8_1, csrp[0], csrp[1], offp[0], offp[1],
                                              degp[0], degp[1], si0, si1, sj0, sj1, b1,
                                              mu1_0, mu1_1, part1, N_NODES);
  fuse1_kernel<<<(N_NODES * 128 + 255) / 256, 256, 0, stream>>>(mu1_0, mu1_1, x2_0, x2_1, N_NODES * 128);

  // ---- layer 2 (C = 64, M = 128) ----
  gemm_kernel<128, false><<<ggrid, 256, 0, stream>>>(x2_0, x2_1, (const short*)wt2, hf8_0, hf8_1,
                                                     att2, si0, si1, sj0, sj1, N_NODES);
  aggr_kernel<128><<<agrid, 256, 0, stream>>>(hf8_0, hf8_1, csrp[0], csrp[1], offp[0], offp[1],
                                              degp[0], degp[1], si0, si1, sj0, sj1, b2,
                                              mu2_0, mu2_1, part2, N_NODES);
  fuse2_kernel<<<(N_NODES * 64 + 255) / 256, 256, 0, stream>>>(mu2_0, mu2_1, out, N_NODES * 64);
  reduce_kernel<<<1, 1024, 0, stream>>>(part1, part2, out + (size_t)2 * N_NODES * 64);
}